// Round 2
// baseline (674.013 us; speedup 1.0000x reference)
//
#include <hip/hip_runtime.h>

typedef unsigned short u16;
typedef unsigned int   u32;

// MFMA fragment types (per guide: 8 bf16 held as shorts = 4 VGPRs)
typedef __attribute__((ext_vector_type(8))) short short8v;
typedef __attribute__((ext_vector_type(4))) float f32x4;

// ---------------- problem constants ----------------
#define BQ   8192
#define DIN  1024
#define DHID 2048
#define DOUT 1024
#define NE   16
#define NSLOT (BQ*2)

// ---------------- ws layout (bytes) ----------------
#define OFF_CNT    ((size_t)0)
#define OFF_CURSOR ((size_t)64)
#define OFF_PREFIX ((size_t)128)
#define OFF_TOPIDX ((size_t)4096)                    // int2[8192]  = 64KB
#define OFF_TOPW   (OFF_TOPIDX + (size_t)65536)      // float2[8192]= 64KB
#define OFF_SLOTS  (OFF_TOPW   + (size_t)65536)      // int[16384]  = 64KB
#define OFF_POSOF  (OFF_SLOTS  + (size_t)65536)      // int[16384]  = 64KB
#define MB (size_t)(1u<<20)
#define OFF_XB     (1*MB)                            // bf16 x       16MB
#define OFF_W1T    (OFF_XB  + 16*MB)                 // bf16 W1^T    64MB
#define OFF_W2T    (OFF_W1T + 64*MB)                 // bf16 W2^T    64MB
#define OFF_H      (OFF_W2T + 64*MB)                 // bf16 H       64MB
#define OFF_POUT   (OFF_H   + 64*MB)                 // f32 partials 64MB

__device__ __forceinline__ u16 f2b(float f) {        // f32 -> bf16 RNE
  u32 u = __float_as_uint(f);
  u += 0x7fffu + ((u >> 16) & 1u);
  return (u16)(u >> 16);
}

__device__ __forceinline__ void gl16(const void* g, void* l) {
  __builtin_amdgcn_global_load_lds(
      (const __attribute__((address_space(1))) u32*)g,
      (__attribute__((address_space(3))) u32*)l, 16, 0, 0);
}

__device__ __forceinline__ int imin(int a, int b) { return a < b ? a : b; }

// ---------------- prepass: x -> bf16 ----------------
__global__ void convx_k(const float* __restrict__ in, u16* __restrict__ out) {
  int i = blockIdx.x * 256 + threadIdx.x;             // 4096*256 = 1,048,576 = B*DIN/8
  const float4* ip = (const float4*)in;
  float4 a = ip[i * 2], b = ip[i * 2 + 1];
  union { u16 u[8]; uint4 v; } r;
  r.u[0]=f2b(a.x); r.u[1]=f2b(a.y); r.u[2]=f2b(a.z); r.u[3]=f2b(a.w);
  r.u[4]=f2b(b.x); r.u[5]=f2b(b.y); r.u[6]=f2b(b.z); r.u[7]=f2b(b.w);
  ((uint4*)out)[i] = r.v;
}

// ------- prepass: per-expert transpose+convert: in[R][C] f32 -> out[C][R] bf16 -------
__global__ void transpose_conv_k(const float* __restrict__ in, u16* __restrict__ out,
                                 int R, int C) {
  __shared__ __align__(16) u16 tile[64][68];          // pad 68 keeps 8B align, spreads banks
  const int e = blockIdx.z;
  const float* ip = in + (size_t)e * R * C;
  u16* op = out + (size_t)e * R * C;
  const int r0 = blockIdx.y * 64, c0 = blockIdx.x * 64;
  const int tr = threadIdx.x >> 4, tc = threadIdx.x & 15;
#pragma unroll
  for (int i = 0; i < 4; ++i) {
    int r = tr + i * 16;
    float4 v = *(const float4*)(ip + (size_t)(r0 + r) * C + c0 + tc * 4);
    ushort4 b; b.x=f2b(v.x); b.y=f2b(v.y); b.z=f2b(v.z); b.w=f2b(v.w);
    *(ushort4*)&tile[r][tc * 4] = b;
  }
  __syncthreads();
#pragma unroll
  for (int i = 0; i < 4; ++i) {
    int c = i * 16 + (threadIdx.x >> 4);              // out row (= in col)
    int rq = threadIdx.x & 15;                        // 4-wide chunk along R
    ushort4 b;
    b.x = tile[rq*4+0][c]; b.y = tile[rq*4+1][c];
    b.z = tile[rq*4+2][c]; b.w = tile[rq*4+3][c];
    *(ushort4*)(op + (size_t)(c0 + c) * R + r0 + rq * 4) = b;
  }
}

// ---------------- gating: fp64 logits, top-2, weights, counts ----------------
__global__ void gating_k(const float* __restrict__ x, const float* __restrict__ Wg,
                         int2* __restrict__ topidx, float2* __restrict__ topw,
                         int* __restrict__ cnt) {
  const int lane = threadIdx.x & 63, wid = threadIdx.x >> 6;
  const int t = blockIdx.x * 4 + wid;
  const float* xr = x + (size_t)t * DIN;
  double p[16];
#pragma unroll
  for (int e = 0; e < 16; ++e) p[e] = 0.0;
#pragma unroll
  for (int it = 0; it < 16; ++it) {
    int d = it * 64 + lane;
    double xd = (double)xr[d];
    const float4* wr = (const float4*)(Wg + d * 16);
    float4 w0 = wr[0], w1 = wr[1], w2 = wr[2], w3 = wr[3];
    p[0]+=xd*w0.x; p[1]+=xd*w0.y; p[2]+=xd*w0.z; p[3]+=xd*w0.w;
    p[4]+=xd*w1.x; p[5]+=xd*w1.y; p[6]+=xd*w1.z; p[7]+=xd*w1.w;
    p[8]+=xd*w2.x; p[9]+=xd*w2.y; p[10]+=xd*w2.z; p[11]+=xd*w2.w;
    p[12]+=xd*w3.x; p[13]+=xd*w3.y; p[14]+=xd*w3.z; p[15]+=xd*w3.w;
  }
#pragma unroll
  for (int e = 0; e < 16; ++e) {
    double v = p[e];
    v += __shfl_xor(v, 32); v += __shfl_xor(v, 16); v += __shfl_xor(v, 8);
    v += __shfl_xor(v, 4);  v += __shfl_xor(v, 2);  v += __shfl_xor(v, 1);
    p[e] = v;
  }
  if (lane == 0) {
    double m0 = -1e300, m1 = -1e300; int i0 = 0, i1 = 0;
#pragma unroll
    for (int e = 0; e < 16; ++e) {
      double v = p[e];
      if (v > m0) { m1 = m0; i1 = i0; m0 = v; i0 = e; }
      else if (v > m1) { m1 = v; i1 = e; }
    }
    double r = exp(m1 - m0);                 // ratio of top-2 softmax probs
    double w0 = 1.0 / (1.0 + r);
    topidx[t] = make_int2(i0, i1);
    topw[t] = make_float2((float)w0, (float)(r / (1.0 + r)));
    atomicAdd(&cnt[i0], 1);
    atomicAdd(&cnt[i1], 1);
  }
}

__global__ void prefix_k(const int* __restrict__ cnt, int* __restrict__ prefix,
                         int* __restrict__ cursor) {
  if (threadIdx.x == 0) {
    int s = 0;
    for (int e = 0; e < 16; ++e) { prefix[e] = s; cursor[e] = s; s += cnt[e]; }
    prefix[16] = s;
  }
}

__global__ void scatter_k(const int2* __restrict__ topidx, int* __restrict__ cursor,
                          int* __restrict__ slots, int* __restrict__ posof) {
  int t = blockIdx.x * 256 + threadIdx.x;
  int2 e = topidx[t];
  int p0 = atomicAdd(&cursor[e.x], 1); slots[p0] = t * 2 + 0; posof[t * 2 + 0] = p0;
  int p1 = atomicAdd(&cursor[e.y], 1); slots[p1] = t * 2 + 1; posof[t * 2 + 1] = p1;
}

// ---------------- grouped GEMM 1: H = relu(gather(xb) @ W1 + b1) ----------------
// grid (DHID/128, 64, E), block 256. A k-contig from xb (gather), B k-contig from W1T.
__global__ __launch_bounds__(256) void mlp1_k(
    const u16* __restrict__ xb, const u16* __restrict__ W1T,
    const float* __restrict__ b1, const int* __restrict__ slots,
    const int* __restrict__ prefix, const int* __restrict__ cnt,
    u16* __restrict__ H) {
  const int e = blockIdx.z, mt = blockIdx.y;
  const int cn = cnt[e];
  if (mt * 128 >= cn) return;
  const int n0 = blockIdx.x * 128;
  const int base = prefix[e];
  __shared__ __align__(16) u16 As[128 * 64], Bs[128 * 64];
  const int tid = threadIdx.x, lane = tid & 63, wid = tid >> 6;
  const int wm = (wid >> 1) * 64, wn = (wid & 1) * 64;
  const int lr = lane >> 3, lp = lane & 7;
  const int swz = lp ^ lr;                       // XOR chunk swizzle (both sides)
  const char* xc = (const char*)xb;
  const char* bc = (const char*)W1T;
  size_t abase[4], bbase[4];
#pragma unroll
  for (int i = 0; i < 4; ++i) {
    int row = wid * 32 + i * 8 + lr;
    int sidx = imin(base + mt * 128 + row, NSLOT - 1);
    int tok = slots[sidx] >> 1;
    abase[i] = (size_t)tok * (DIN * 2) + (size_t)swz * 16;
    bbase[i] = ((size_t)e * DHID + n0 + row) * (DIN * 2) + (size_t)swz * 16;
  }
  f32x4 acc[4][4];
#pragma unroll
  for (int m = 0; m < 4; ++m)
#pragma unroll
    for (int n = 0; n < 4; ++n) acc[m][n] = (f32x4){0.f, 0.f, 0.f, 0.f};

  for (int kt = 0; kt < DIN / 64; ++kt) {
#pragma unroll
    for (int i = 0; i < 4; ++i) gl16(xc + abase[i] + kt * 128, &As[(wid * 32 + i * 8) * 64]);
#pragma unroll
    for (int i = 0; i < 4; ++i) gl16(bc + bbase[i] + kt * 128, &Bs[(wid * 32 + i * 8) * 64]);
    __syncthreads();
#pragma unroll
    for (int kk = 0; kk < 2; ++kk) {
      short8v av[4], bv[4];
#pragma unroll
      for (int m = 0; m < 4; ++m) {
        int row = wm + m * 16 + (lane & 15);
        int phys = (kk * 4 + (lane >> 4)) ^ (lane & 7);
        av[m] = *(const short8v*)&As[row * 64 + phys * 8];
      }
#pragma unroll
      for (int n = 0; n < 4; ++n) {
        int row = wn + n * 16 + (lane & 15);
        int phys = (kk * 4 + (lane >> 4)) ^ (lane & 7);
        bv[n] = *(const short8v*)&Bs[row * 64 + phys * 8];
      }
#pragma unroll
      for (int m = 0; m < 4; ++m)
#pragma unroll
        for (int n = 0; n < 4; ++n)
          acc[m][n] = __builtin_amdgcn_mfma_f32_16x16x32_bf16(av[m], bv[n], acc[m][n], 0, 0, 0);
    }
    __syncthreads();
  }
  const float* b1e = b1 + e * DHID;
  const int rbase = mt * 128;
#pragma unroll
  for (int m = 0; m < 4; ++m)
#pragma unroll
    for (int j = 0; j < 4; ++j) {
      int row = wm + m * 16 + (lane >> 4) * 4 + j;
      if (rbase + row < cn) {
        size_t orow = (size_t)(base + rbase + row) * DHID;
#pragma unroll
        for (int n = 0; n < 4; ++n) {
          int col = n0 + wn + n * 16 + (lane & 15);
          float v = acc[m][n][j] + b1e[col];
          H[orow + col] = f2b(fmaxf(v, 0.f));
        }
      }
    }
}

// ---------------- grouped GEMM 2: pout = w * (H @ W2 + b2) ----------------
// grid (DOUT/128, 64, E), block 256.
__global__ __launch_bounds__(256) void mlp2_k(
    const u16* __restrict__ H, const u16* __restrict__ W2T,
    const float* __restrict__ b2, const int* __restrict__ slots,
    const int* __restrict__ prefix, const int* __restrict__ cnt,
    const float* __restrict__ topw, float* __restrict__ pout) {
  const int e = blockIdx.z, mt = blockIdx.y;
  const int cn = cnt[e];
  if (mt * 128 >= cn) return;
  const int n0 = blockIdx.x * 128;
  const int base = prefix[e];
  __shared__ __align__(16) u16 As[128 * 64], Bs[128 * 64];
  const int tid = threadIdx.x, lane = tid & 63, wid = tid >> 6;
  const int wm = (wid >> 1) * 64, wn = (wid & 1) * 64;
  const int lr = lane >> 3, lp = lane & 7;
  const int swz = lp ^ lr;
  const char* hc = (const char*)H;
  const char* bc = (const char*)W2T;
  size_t abase[4], bbase[4];
#pragma unroll
  for (int i = 0; i < 4; ++i) {
    int row = wid * 32 + i * 8 + lr;
    int sidx = imin(base + mt * 128 + row, NSLOT - 1);
    abase[i] = (size_t)sidx * (DHID * 2) + (size_t)swz * 16;
    bbase[i] = ((size_t)e * DOUT + n0 + row) * (DHID * 2) + (size_t)swz * 16;
  }
  f32x4 acc[4][4];
#pragma unroll
  for (int m = 0; m < 4; ++m)
#pragma unroll
    for (int n = 0; n < 4; ++n) acc[m][n] = (f32x4){0.f, 0.f, 0.f, 0.f};

  for (int kt = 0; kt < DHID / 64; ++kt) {
#pragma unroll
    for (int i = 0; i < 4; ++i) gl16(hc + abase[i] + kt * 128, &As[(wid * 32 + i * 8) * 64]);
#pragma unroll
    for (int i = 0; i < 4; ++i) gl16(bc + bbase[i] + kt * 128, &Bs[(wid * 32 + i * 8) * 64]);
    __syncthreads();
#pragma unroll
    for (int kk = 0; kk < 2; ++kk) {
      short8v av[4], bv[4];
#pragma unroll
      for (int m = 0; m < 4; ++m) {
        int row = wm + m * 16 + (lane & 15);
        int phys = (kk * 4 + (lane >> 4)) ^ (lane & 7);
        av[m] = *(const short8v*)&As[row * 64 + phys * 8];
      }
#pragma unroll
      for (int n = 0; n < 4; ++n) {
        int row = wn + n * 16 + (lane & 15);
        int phys = (kk * 4 + (lane >> 4)) ^ (lane & 7);
        bv[n] = *(const short8v*)&Bs[row * 64 + phys * 8];
      }
#pragma unroll
      for (int m = 0; m < 4; ++m)
#pragma unroll
        for (int n = 0; n < 4; ++n)
          acc[m][n] = __builtin_amdgcn_mfma_f32_16x16x32_bf16(av[m], bv[n], acc[m][n], 0, 0, 0);
    }
    __syncthreads();
  }
  const float* b2e = b2 + e * DOUT;
  const int rbase = mt * 128;
#pragma unroll
  for (int m = 0; m < 4; ++m)
#pragma unroll
    for (int j = 0; j < 4; ++j) {
      int row = wm + m * 16 + (lane >> 4) * 4 + j;
      if (rbase + row < cn) {
        int spos = base + rbase + row;
        int sc = slots[spos];
        float w = topw[sc];
        size_t orow = (size_t)spos * DOUT;
#pragma unroll
        for (int n = 0; n < 4; ++n) {
          int col = n0 + wn + n * 16 + (lane & 15);
          pout[orow + col] = w * (acc[m][n][j] + b2e[col]);
        }
      }
    }
}

// ---------------- combine: out[t] = pout[pos(t,0)] + pout[pos(t,1)] ----------------
__global__ void combine_k(const float* __restrict__ pout, const int* __restrict__ posof,
                          float* __restrict__ out) {
  int t = blockIdx.x;
  int p0 = posof[t * 2], p1 = posof[t * 2 + 1];
  const float4* r0 = (const float4*)(pout + (size_t)p0 * DOUT);
  const float4* r1 = (const float4*)(pout + (size_t)p1 * DOUT);
  float4 a = r0[threadIdx.x], b = r1[threadIdx.x];
  float4 o; o.x = a.x + b.x; o.y = a.y + b.y; o.z = a.z + b.z; o.w = a.w + b.w;
  ((float4*)(out + (size_t)t * DOUT))[threadIdx.x] = o;
}

extern "C" void kernel_launch(void* const* d_in, const int* in_sizes, int n_in,
                              void* d_out, int out_size, void* d_ws, size_t ws_size,
                              hipStream_t stream) {
  const float* x  = (const float*)d_in[0];
  const float* Wg = (const float*)d_in[1];
  const float* W1 = (const float*)d_in[2];
  const float* b1 = (const float*)d_in[3];
  const float* W2 = (const float*)d_in[4];
  const float* b2 = (const float*)d_in[5];
  float* out = (float*)d_out;
  char* ws = (char*)d_ws;

  int*    cnt    = (int*)(ws + OFF_CNT);
  int*    cursor = (int*)(ws + OFF_CURSOR);
  int*    prefix = (int*)(ws + OFF_PREFIX);
  int2*   topidx = (int2*)(ws + OFF_TOPIDX);
  float2* topw2  = (float2*)(ws + OFF_TOPW);
  float*  topw   = (float*)(ws + OFF_TOPW);
  int*    slots  = (int*)(ws + OFF_SLOTS);
  int*    posof  = (int*)(ws + OFF_POSOF);
  u16*    xb     = (u16*)(ws + OFF_XB);
  u16*    W1T    = (u16*)(ws + OFF_W1T);
  u16*    W2T    = (u16*)(ws + OFF_W2T);
  u16*    H      = (u16*)(ws + OFF_H);
  float*  pout   = (float*)(ws + OFF_POUT);

  (void)hipMemsetAsync(ws, 0, 256, stream);  // zero cnt/cursor/prefix region

  convx_k<<<4096, 256, 0, stream>>>(x, xb);
  transpose_conv_k<<<dim3(DHID / 64, DIN / 64, NE), 256, 0, stream>>>(W1, W1T, DIN, DHID);
  transpose_conv_k<<<dim3(DHID / 64 / 2, DIN / 64 * 2, NE), 256, 0, stream>>>(W2, W2T, DHID, DOUT);
  gating_k<<<BQ / 4, 256, 0, stream>>>(x, Wg, topidx, topw2, cnt);
  prefix_k<<<1, 64, 0, stream>>>(cnt, prefix, cursor);
  scatter_k<<<BQ / 256, 256, 0, stream>>>(topidx, cursor, slots, posof);
  mlp1_k<<<dim3(DHID / 128, 64, NE), 256, 0, stream>>>(xb, W1T, b1, slots, prefix, cnt, H);
  mlp2_k<<<dim3(DOUT / 128, 64, NE), 256, 0, stream>>>(H, W2T, b2, slots, prefix, cnt, topw, pout);
  combine_k<<<BQ, 256, 0, stream>>>(pout, posof, out);
}

// Round 3
// 490.486 us; speedup vs baseline: 1.3742x; 1.3742x over previous
//
#include <hip/hip_runtime.h>

typedef unsigned short u16;
typedef unsigned int   u32;

// MFMA fragment types (per guide: 8 bf16 held as shorts = 4 VGPRs)
typedef __attribute__((ext_vector_type(8))) short short8v;
typedef __attribute__((ext_vector_type(4))) float f32x4;

// ---------------- problem constants ----------------
#define BQ   8192
#define DIN  1024
#define DHID 2048
#define DOUT 1024
#define NE   16
#define NSLOT (BQ*2)

// ---------------- ws layout (bytes) ----------------
#define OFF_CNT    ((size_t)0)
#define OFF_CURSOR ((size_t)64)
#define OFF_PREFIX ((size_t)128)
#define OFF_TOPIDX ((size_t)4096)                    // int2[8192]  = 64KB
#define OFF_TOPW   (OFF_TOPIDX + (size_t)65536)      // float2[8192]= 64KB
#define OFF_SLOTS  (OFF_TOPW   + (size_t)65536)      // int[16384]  = 64KB
#define OFF_POSOF  (OFF_SLOTS  + (size_t)65536)      // int[16384]  = 64KB
#define MB (size_t)(1u<<20)
#define OFF_XB     (1*MB)                            // bf16 x       16MB
#define OFF_W1T    (OFF_XB  + 16*MB)                 // bf16 W1^T    64MB
#define OFF_W2T    (OFF_W1T + 64*MB)                 // bf16 W2^T    64MB
#define OFF_H      (OFF_W2T + 64*MB)                 // bf16 H       64MB
#define OFF_POUT   (OFF_H   + 64*MB)                 // f32 partials 64MB

__device__ __forceinline__ u16 f2b(float f) {        // f32 -> bf16 RNE
  u32 u = __float_as_uint(f);
  u += 0x7fffu + ((u >> 16) & 1u);
  return (u16)(u >> 16);
}

__device__ __forceinline__ void gl16(const void* g, void* l) {
  __builtin_amdgcn_global_load_lds(
      (const __attribute__((address_space(1))) u32*)g,
      (__attribute__((address_space(3))) u32*)l, 16, 0, 0);
}

__device__ __forceinline__ int imin(int a, int b) { return a < b ? a : b; }

// ---------------- prepass: x -> bf16 ----------------
__global__ void convx_k(const float* __restrict__ in, u16* __restrict__ out) {
  int i = blockIdx.x * 256 + threadIdx.x;             // 4096*256 = 1,048,576 = B*DIN/8
  const float4* ip = (const float4*)in;
  float4 a = ip[i * 2], b = ip[i * 2 + 1];
  union { u16 u[8]; uint4 v; } r;
  r.u[0]=f2b(a.x); r.u[1]=f2b(a.y); r.u[2]=f2b(a.z); r.u[3]=f2b(a.w);
  r.u[4]=f2b(b.x); r.u[5]=f2b(b.y); r.u[6]=f2b(b.z); r.u[7]=f2b(b.w);
  ((uint4*)out)[i] = r.v;
}

// ------- prepass: per-expert transpose+convert: in[R][C] f32 -> out[C][R] bf16 -------
__global__ void transpose_conv_k(const float* __restrict__ in, u16* __restrict__ out,
                                 int R, int C) {
  __shared__ __align__(16) u16 tile[64][68];          // pad 68 keeps 8B align, spreads banks
  const int e = blockIdx.z;
  const float* ip = in + (size_t)e * R * C;
  u16* op = out + (size_t)e * R * C;
  const int r0 = blockIdx.y * 64, c0 = blockIdx.x * 64;
  const int tr = threadIdx.x >> 4, tc = threadIdx.x & 15;
#pragma unroll
  for (int i = 0; i < 4; ++i) {
    int r = tr + i * 16;
    float4 v = *(const float4*)(ip + (size_t)(r0 + r) * C + c0 + tc * 4);
    ushort4 b; b.x=f2b(v.x); b.y=f2b(v.y); b.z=f2b(v.z); b.w=f2b(v.w);
    *(ushort4*)&tile[r][tc * 4] = b;
  }
  __syncthreads();
#pragma unroll
  for (int i = 0; i < 4; ++i) {
    int c = i * 16 + (threadIdx.x >> 4);              // out row (= in col)
    int rq = threadIdx.x & 15;                        // 4-wide chunk along R
    ushort4 b;
    b.x = tile[rq*4+0][c]; b.y = tile[rq*4+1][c];
    b.z = tile[rq*4+2][c]; b.w = tile[rq*4+3][c];
    *(ushort4*)(op + (size_t)(c0 + c) * R + r0 + rq * 4) = b;
  }
}

// ---------------- gating v2: Wg in LDS, 8 threads/token, fp64 accum ----------------
// grid 256 blocks x 256 threads; block handles 32 tokens; thread (tt,q) covers
// token t0+tt, k in [q*128, q*128+128). Wg staged in LDS with 16B-chunk XOR
// swizzle (pc = c ^ ((k>>7)&3)) so the 8 concurrent k-stripes spread banks.
__global__ __launch_bounds__(256) void gating2_k(
    const float* __restrict__ x, const float* __restrict__ Wg,
    int2* __restrict__ topidx, float2* __restrict__ topw, int* __restrict__ cnt) {
  __shared__ __align__(16) float wg[1024 * 16];       // 64KB
  __shared__ int hist[16];
  const int tid = threadIdx.x;
  const int t0 = blockIdx.x * 32;
  if (tid < 16) hist[tid] = 0;
  // stage Wg (4096 float4 chunks), coalesced read, swizzled write
  for (int idx = tid; idx < 4096; idx += 256) {
    int k = idx >> 2, c = idx & 3;
    float4 v = ((const float4*)Wg)[idx];
    int pc = c ^ ((k >> 7) & 3);
    *(float4*)&wg[k * 16 + pc * 4] = v;
  }
  __syncthreads();
  const int tt = tid >> 3, q = tid & 7;
  const int f = q & 3;
  double p[16];
#pragma unroll
  for (int e = 0; e < 16; ++e) p[e] = 0.0;
  const float4* xr4 = (const float4*)(x + (size_t)(t0 + tt) * DIN + q * 128);
  for (int jj = 0; jj < 32; ++jj) {
    float4 xv = xr4[jj];
#pragma unroll
    for (int u = 0; u < 4; ++u) {
      int row = q * 128 + jj * 4 + u;
      float xs = (u == 0) ? xv.x : (u == 1) ? xv.y : (u == 2) ? xv.z : xv.w;
      double xd = (double)xs;
#pragma unroll
      for (int c = 0; c < 4; ++c) {
        float4 w = *(const float4*)&wg[row * 16 + (c ^ f) * 4];
        p[c * 4 + 0] += xd * (double)w.x;
        p[c * 4 + 1] += xd * (double)w.y;
        p[c * 4 + 2] += xd * (double)w.z;
        p[c * 4 + 3] += xd * (double)w.w;
      }
    }
  }
  // reduce the 8 k-stripes (lanes tid^1,^2,^4 share a token)
#pragma unroll
  for (int e = 0; e < 16; ++e) {
    double v = p[e];
    v += __shfl_xor(v, 1);
    v += __shfl_xor(v, 2);
    v += __shfl_xor(v, 4);
    p[e] = v;
  }
  if (q == 0) {
    double m0 = -1e300, m1 = -1e300; int i0 = 0, i1 = 0;
#pragma unroll
    for (int e = 0; e < 16; ++e) {
      double v = p[e];
      if (v > m0) { m1 = m0; i1 = i0; m0 = v; i0 = e; }
      else if (v > m1) { m1 = v; i1 = e; }
    }
    double r = exp(m1 - m0);                 // ratio of top-2 softmax probs
    double w0 = 1.0 / (1.0 + r);
    int t = t0 + tt;
    topidx[t] = make_int2(i0, i1);
    topw[t] = make_float2((float)w0, (float)(r / (1.0 + r)));
    atomicAdd(&hist[i0], 1);
    atomicAdd(&hist[i1], 1);
  }
  __syncthreads();
  if (tid < 16 && hist[tid] > 0) atomicAdd(&cnt[tid], hist[tid]);
}

__global__ void prefix_k(const int* __restrict__ cnt, int* __restrict__ prefix,
                         int* __restrict__ cursor) {
  if (threadIdx.x == 0) {
    int s = 0;
    for (int e = 0; e < 16; ++e) { prefix[e] = s; cursor[e] = s; s += cnt[e]; }
    prefix[16] = s;
  }
}

__global__ void scatter_k(const int2* __restrict__ topidx, int* __restrict__ cursor,
                          int* __restrict__ slots, int* __restrict__ posof) {
  int t = blockIdx.x * 256 + threadIdx.x;
  int2 e = topidx[t];
  int p0 = atomicAdd(&cursor[e.x], 1); slots[p0] = t * 2 + 0; posof[t * 2 + 0] = p0;
  int p1 = atomicAdd(&cursor[e.y], 1); slots[p1] = t * 2 + 1; posof[t * 2 + 1] = p1;
}

// ---------------- grouped GEMM 1: H = relu(gather(xb) @ W1 + b1) ----------------
// grid (DHID/128, 64, E), block 256. A k-contig from xb (gather), B k-contig from W1T.
__global__ __launch_bounds__(256) void mlp1_k(
    const u16* __restrict__ xb, const u16* __restrict__ W1T,
    const float* __restrict__ b1, const int* __restrict__ slots,
    const int* __restrict__ prefix, const int* __restrict__ cnt,
    u16* __restrict__ H) {
  const int e = blockIdx.z, mt = blockIdx.y;
  const int cn = cnt[e];
  if (mt * 128 >= cn) return;
  const int n0 = blockIdx.x * 128;
  const int base = prefix[e];
  __shared__ __align__(16) u16 As[128 * 64], Bs[128 * 64];
  const int tid = threadIdx.x, lane = tid & 63, wid = tid >> 6;
  const int wm = (wid >> 1) * 64, wn = (wid & 1) * 64;
  const int lr = lane >> 3, lp = lane & 7;
  const int swz = lp ^ lr;                       // XOR chunk swizzle (both sides)
  const char* xc = (const char*)xb;
  const char* bc = (const char*)W1T;
  size_t abase[4], bbase[4];
#pragma unroll
  for (int i = 0; i < 4; ++i) {
    int row = wid * 32 + i * 8 + lr;
    int sidx = imin(base + mt * 128 + row, NSLOT - 1);
    int tok = slots[sidx] >> 1;
    abase[i] = (size_t)tok * (DIN * 2) + (size_t)swz * 16;
    bbase[i] = ((size_t)e * DHID + n0 + row) * (DIN * 2) + (size_t)swz * 16;
  }
  f32x4 acc[4][4];
#pragma unroll
  for (int m = 0; m < 4; ++m)
#pragma unroll
    for (int n = 0; n < 4; ++n) acc[m][n] = (f32x4){0.f, 0.f, 0.f, 0.f};

  for (int kt = 0; kt < DIN / 64; ++kt) {
#pragma unroll
    for (int i = 0; i < 4; ++i) gl16(xc + abase[i] + kt * 128, &As[(wid * 32 + i * 8) * 64]);
#pragma unroll
    for (int i = 0; i < 4; ++i) gl16(bc + bbase[i] + kt * 128, &Bs[(wid * 32 + i * 8) * 64]);
    __syncthreads();
#pragma unroll
    for (int kk = 0; kk < 2; ++kk) {
      short8v av[4], bv[4];
#pragma unroll
      for (int m = 0; m < 4; ++m) {
        int row = wm + m * 16 + (lane & 15);
        int phys = (kk * 4 + (lane >> 4)) ^ (lane & 7);
        av[m] = *(const short8v*)&As[row * 64 + phys * 8];
      }
#pragma unroll
      for (int n = 0; n < 4; ++n) {
        int row = wn + n * 16 + (lane & 15);
        int phys = (kk * 4 + (lane >> 4)) ^ (lane & 7);
        bv[n] = *(const short8v*)&Bs[row * 64 + phys * 8];
      }
#pragma unroll
      for (int m = 0; m < 4; ++m)
#pragma unroll
        for (int n = 0; n < 4; ++n)
          acc[m][n] = __builtin_amdgcn_mfma_f32_16x16x32_bf16(av[m], bv[n], acc[m][n], 0, 0, 0);
    }
    __syncthreads();
  }
  const float* b1e = b1 + e * DHID;
  const int rbase = mt * 128;
#pragma unroll
  for (int m = 0; m < 4; ++m)
#pragma unroll
    for (int j = 0; j < 4; ++j) {
      int row = wm + m * 16 + (lane >> 4) * 4 + j;
      if (rbase + row < cn) {
        size_t orow = (size_t)(base + rbase + row) * DHID;
#pragma unroll
        for (int n = 0; n < 4; ++n) {
          int col = n0 + wn + n * 16 + (lane & 15);
          float v = acc[m][n][j] + b1e[col];
          H[orow + col] = f2b(fmaxf(v, 0.f));
        }
      }
    }
}

// ---------------- grouped GEMM 2: pout = w * (H @ W2 + b2) ----------------
// grid (DOUT/128, 64, E), block 256.
__global__ __launch_bounds__(256) void mlp2_k(
    const u16* __restrict__ H, const u16* __restrict__ W2T,
    const float* __restrict__ b2, const int* __restrict__ slots,
    const int* __restrict__ prefix, const int* __restrict__ cnt,
    const float* __restrict__ topw, float* __restrict__ pout) {
  const int e = blockIdx.z, mt = blockIdx.y;
  const int cn = cnt[e];
  if (mt * 128 >= cn) return;
  const int n0 = blockIdx.x * 128;
  const int base = prefix[e];
  __shared__ __align__(16) u16 As[128 * 64], Bs[128 * 64];
  const int tid = threadIdx.x, lane = tid & 63, wid = tid >> 6;
  const int wm = (wid >> 1) * 64, wn = (wid & 1) * 64;
  const int lr = lane >> 3, lp = lane & 7;
  const int swz = lp ^ lr;
  const char* hc = (const char*)H;
  const char* bc = (const char*)W2T;
  size_t abase[4], bbase[4];
#pragma unroll
  for (int i = 0; i < 4; ++i) {
    int row = wid * 32 + i * 8 + lr;
    int sidx = imin(base + mt * 128 + row, NSLOT - 1);
    abase[i] = (size_t)sidx * (DHID * 2) + (size_t)swz * 16;
    bbase[i] = ((size_t)e * DOUT + n0 + row) * (DHID * 2) + (size_t)swz * 16;
  }
  f32x4 acc[4][4];
#pragma unroll
  for (int m = 0; m < 4; ++m)
#pragma unroll
    for (int n = 0; n < 4; ++n) acc[m][n] = (f32x4){0.f, 0.f, 0.f, 0.f};

  for (int kt = 0; kt < DHID / 64; ++kt) {
#pragma unroll
    for (int i = 0; i < 4; ++i) gl16(hc + abase[i] + kt * 128, &As[(wid * 32 + i * 8) * 64]);
#pragma unroll
    for (int i = 0; i < 4; ++i) gl16(bc + bbase[i] + kt * 128, &Bs[(wid * 32 + i * 8) * 64]);
    __syncthreads();
#pragma unroll
    for (int kk = 0; kk < 2; ++kk) {
      short8v av[4], bv[4];
#pragma unroll
      for (int m = 0; m < 4; ++m) {
        int row = wm + m * 16 + (lane & 15);
        int phys = (kk * 4 + (lane >> 4)) ^ (lane & 7);
        av[m] = *(const short8v*)&As[row * 64 + phys * 8];
      }
#pragma unroll
      for (int n = 0; n < 4; ++n) {
        int row = wn + n * 16 + (lane & 15);
        int phys = (kk * 4 + (lane >> 4)) ^ (lane & 7);
        bv[n] = *(const short8v*)&Bs[row * 64 + phys * 8];
      }
#pragma unroll
      for (int m = 0; m < 4; ++m)
#pragma unroll
        for (int n = 0; n < 4; ++n)
          acc[m][n] = __builtin_amdgcn_mfma_f32_16x16x32_bf16(av[m], bv[n], acc[m][n], 0, 0, 0);
    }
    __syncthreads();
  }
  const float* b2e = b2 + e * DOUT;
  const int rbase = mt * 128;
#pragma unroll
  for (int m = 0; m < 4; ++m)
#pragma unroll
    for (int j = 0; j < 4; ++j) {
      int row = wm + m * 16 + (lane >> 4) * 4 + j;
      if (rbase + row < cn) {
        int spos = base + rbase + row;
        int sc = slots[spos];
        float w = topw[sc];
        size_t orow = (size_t)spos * DOUT;
#pragma unroll
        for (int n = 0; n < 4; ++n) {
          int col = n0 + wn + n * 16 + (lane & 15);
          pout[orow + col] = w * (acc[m][n][j] + b2e[col]);
        }
      }
    }
}

// ---------------- combine: out[t] = pout[pos(t,0)] + pout[pos(t,1)] ----------------
__global__ void combine_k(const float* __restrict__ pout, const int* __restrict__ posof,
                          float* __restrict__ out) {
  int t = blockIdx.x;
  int p0 = posof[t * 2], p1 = posof[t * 2 + 1];
  const float4* r0 = (const float4*)(pout + (size_t)p0 * DOUT);
  const float4* r1 = (const float4*)(pout + (size_t)p1 * DOUT);
  float4 a = r0[threadIdx.x], b = r1[threadIdx.x];
  float4 o; o.x = a.x + b.x; o.y = a.y + b.y; o.z = a.z + b.z; o.w = a.w + b.w;
  ((float4*)(out + (size_t)t * DOUT))[threadIdx.x] = o;
}

extern "C" void kernel_launch(void* const* d_in, const int* in_sizes, int n_in,
                              void* d_out, int out_size, void* d_ws, size_t ws_size,
                              hipStream_t stream) {
  const float* x  = (const float*)d_in[0];
  const float* Wg = (const float*)d_in[1];
  const float* W1 = (const float*)d_in[2];
  const float* b1 = (const float*)d_in[3];
  const float* W2 = (const float*)d_in[4];
  const float* b2 = (const float*)d_in[5];
  float* out = (float*)d_out;
  char* ws = (char*)d_ws;

  int*    cnt    = (int*)(ws + OFF_CNT);
  int*    cursor = (int*)(ws + OFF_CURSOR);
  int*    prefix = (int*)(ws + OFF_PREFIX);
  int2*   topidx = (int2*)(ws + OFF_TOPIDX);
  float2* topw2  = (float2*)(ws + OFF_TOPW);
  float*  topw   = (float*)(ws + OFF_TOPW);
  int*    slots  = (int*)(ws + OFF_SLOTS);
  int*    posof  = (int*)(ws + OFF_POSOF);
  u16*    xb     = (u16*)(ws + OFF_XB);
  u16*    W1T    = (u16*)(ws + OFF_W1T);
  u16*    W2T    = (u16*)(ws + OFF_W2T);
  u16*    H      = (u16*)(ws + OFF_H);
  float*  pout   = (float*)(ws + OFF_POUT);

  (void)hipMemsetAsync(ws, 0, 256, stream);  // zero cnt/cursor/prefix region

  convx_k<<<4096, 256, 0, stream>>>(x, xb);
  transpose_conv_k<<<dim3(DHID / 64, DIN / 64, NE), 256, 0, stream>>>(W1, W1T, DIN, DHID);
  transpose_conv_k<<<dim3(DHID / 64 / 2, DIN / 64 * 2, NE), 256, 0, stream>>>(W2, W2T, DHID, DOUT);
  gating2_k<<<256, 256, 0, stream>>>(x, Wg, topidx, topw2, cnt);
  prefix_k<<<1, 64, 0, stream>>>(cnt, prefix, cursor);
  scatter_k<<<BQ / 256, 256, 0, stream>>>(topidx, cursor, slots, posof);
  mlp1_k<<<dim3(DHID / 128, 64, NE), 256, 0, stream>>>(xb, W1T, b1, slots, prefix, cnt, H);
  mlp2_k<<<dim3(DOUT / 128, 64, NE), 256, 0, stream>>>(H, W2T, b2, slots, prefix, cnt, topw, pout);
  combine_k<<<BQ, 256, 0, stream>>>(pout, posof, out);
}

// Round 4
// 460.300 us; speedup vs baseline: 1.4643x; 1.0656x over previous
//
#include <hip/hip_runtime.h>

typedef unsigned short u16;
typedef unsigned int   u32;

// MFMA fragment types (per guide: 8 bf16 held as shorts = 4 VGPRs)
typedef __attribute__((ext_vector_type(8))) short short8v;
typedef __attribute__((ext_vector_type(4))) float f32x4;

// ---------------- problem constants ----------------
#define BQ   8192
#define DIN  1024
#define DHID 2048
#define DOUT 1024
#define NE   16
#define NSLOT (BQ*2)
#define BK   32
#define MAXTILES 144

// ---------------- ws layout (bytes) ----------------
#define OFF_CNT    ((size_t)0)
#define OFF_CURSOR ((size_t)64)
#define OFF_PREFIX ((size_t)128)
#define OFF_TTAB   ((size_t)512)                     // u32[144]
#define OFF_NTT    ((size_t)1280)                    // int
#define OFF_TOPIDX ((size_t)4096)                    // int2[8192]  = 64KB
#define OFF_TOPW   (OFF_TOPIDX + (size_t)65536)      // float2[8192]= 64KB
#define OFF_SLOTS  (OFF_TOPW   + (size_t)65536)      // int[16384]  = 64KB
#define OFF_POSOF  (OFF_SLOTS  + (size_t)65536)      // int[16384]  = 64KB
#define MB (size_t)(1u<<20)
#define OFF_XB     (1*MB)                            // bf16 x       16MB
#define OFF_W1T    (OFF_XB  + 16*MB)                 // bf16 W1^T    64MB
#define OFF_W2T    (OFF_W1T + 64*MB)                 // bf16 W2^T    64MB
#define OFF_H      (OFF_W2T + 64*MB)                 // bf16 H       64MB
#define OFF_POUT   (OFF_H   + 64*MB)                 // f32 partials 64MB

__device__ __forceinline__ u16 f2b(float f) {        // f32 -> bf16 RNE
  u32 u = __float_as_uint(f);
  u += 0x7fffu + ((u >> 16) & 1u);
  return (u16)(u >> 16);
}

__device__ __forceinline__ void gl16(const void* g, void* l) {
  __builtin_amdgcn_global_load_lds(
      (const __attribute__((address_space(1))) u32*)g,
      (__attribute__((address_space(3))) u32*)l, 16, 0, 0);
}

__device__ __forceinline__ int imin(int a, int b) { return a < b ? a : b; }

// ---------------- prepass: x -> bf16 ----------------
__global__ void convx_k(const float* __restrict__ in, u16* __restrict__ out) {
  int i = blockIdx.x * 256 + threadIdx.x;             // 4096*256 = B*DIN/8
  const float4* ip = (const float4*)in;
  float4 a = ip[i * 2], b = ip[i * 2 + 1];
  union { u16 u[8]; uint4 v; } r;
  r.u[0]=f2b(a.x); r.u[1]=f2b(a.y); r.u[2]=f2b(a.z); r.u[3]=f2b(a.w);
  r.u[4]=f2b(b.x); r.u[5]=f2b(b.y); r.u[6]=f2b(b.z); r.u[7]=f2b(b.w);
  ((uint4*)out)[i] = r.v;
}

// ------- prepass: per-expert transpose+convert: in[R][C] f32 -> out[C][R] bf16 -------
__global__ void transpose_conv_k(const float* __restrict__ in, u16* __restrict__ out,
                                 int R, int C) {
  __shared__ __align__(16) u16 tile[64][68];
  const int e = blockIdx.z;
  const float* ip = in + (size_t)e * R * C;
  u16* op = out + (size_t)e * R * C;
  const int r0 = blockIdx.y * 64, c0 = blockIdx.x * 64;
  const int tr = threadIdx.x >> 4, tc = threadIdx.x & 15;
#pragma unroll
  for (int i = 0; i < 4; ++i) {
    int r = tr + i * 16;
    float4 v = *(const float4*)(ip + (size_t)(r0 + r) * C + c0 + tc * 4);
    ushort4 b; b.x=f2b(v.x); b.y=f2b(v.y); b.z=f2b(v.z); b.w=f2b(v.w);
    *(ushort4*)&tile[r][tc * 4] = b;
  }
  __syncthreads();
#pragma unroll
  for (int i = 0; i < 4; ++i) {
    int c = i * 16 + (threadIdx.x >> 4);
    int rq = threadIdx.x & 15;
    ushort4 b;
    b.x = tile[rq*4+0][c]; b.y = tile[rq*4+1][c];
    b.z = tile[rq*4+2][c]; b.w = tile[rq*4+3][c];
    *(ushort4*)(op + (size_t)(c0 + c) * R + r0 + rq * 4) = b;
  }
}

// ---------------- gating v2: Wg in LDS, 8 threads/token, fp64 accum ----------------
__global__ __launch_bounds__(256) void gating2_k(
    const float* __restrict__ x, const float* __restrict__ Wg,
    int2* __restrict__ topidx, float2* __restrict__ topw, int* __restrict__ cnt) {
  __shared__ __align__(16) float wg[1024 * 16];       // 64KB
  __shared__ int hist[16];
  const int tid = threadIdx.x;
  const int t0 = blockIdx.x * 32;
  if (tid < 16) hist[tid] = 0;
  for (int idx = tid; idx < 4096; idx += 256) {
    int k = idx >> 2, c = idx & 3;
    float4 v = ((const float4*)Wg)[idx];
    int pc = c ^ ((k >> 7) & 3);
    *(float4*)&wg[k * 16 + pc * 4] = v;
  }
  __syncthreads();
  const int tt = tid >> 3, q = tid & 7;
  const int f = q & 3;
  double p[16];
#pragma unroll
  for (int e = 0; e < 16; ++e) p[e] = 0.0;
  const float4* xr4 = (const float4*)(x + (size_t)(t0 + tt) * DIN + q * 128);
  for (int jj = 0; jj < 32; ++jj) {
    float4 xv = xr4[jj];
#pragma unroll
    for (int u = 0; u < 4; ++u) {
      int row = q * 128 + jj * 4 + u;
      float xs = (u == 0) ? xv.x : (u == 1) ? xv.y : (u == 2) ? xv.z : xv.w;
      double xd = (double)xs;
#pragma unroll
      for (int c = 0; c < 4; ++c) {
        float4 w = *(const float4*)&wg[row * 16 + (c ^ f) * 4];
        p[c * 4 + 0] += xd * (double)w.x;
        p[c * 4 + 1] += xd * (double)w.y;
        p[c * 4 + 2] += xd * (double)w.z;
        p[c * 4 + 3] += xd * (double)w.w;
      }
    }
  }
#pragma unroll
  for (int e = 0; e < 16; ++e) {
    double v = p[e];
    v += __shfl_xor(v, 1);
    v += __shfl_xor(v, 2);
    v += __shfl_xor(v, 4);
    p[e] = v;
  }
  if (q == 0) {
    double m0 = -1e300, m1 = -1e300; int i0 = 0, i1 = 0;
#pragma unroll
    for (int e = 0; e < 16; ++e) {
      double v = p[e];
      if (v > m0) { m1 = m0; i1 = i0; m0 = v; i0 = e; }
      else if (v > m1) { m1 = v; i1 = e; }
    }
    double r = exp(m1 - m0);
    double w0 = 1.0 / (1.0 + r);
    int t = t0 + tt;
    topidx[t] = make_int2(i0, i1);
    topw[t] = make_float2((float)w0, (float)(r / (1.0 + r)));
    atomicAdd(&hist[i0], 1);
    atomicAdd(&hist[i1], 1);
  }
  __syncthreads();
  if (tid < 16 && hist[tid] > 0) atomicAdd(&cnt[tid], hist[tid]);
}

// prefix + compact tile table: entries (e<<16)|mt, mt over ceil(cnt/128)
__global__ void prefix_k(const int* __restrict__ cnt, int* __restrict__ prefix,
                         int* __restrict__ cursor, u32* __restrict__ ttab,
                         int* __restrict__ ntt) {
  if (threadIdx.x == 0) {
    int s = 0, nt = 0;
    for (int e = 0; e < 16; ++e) {
      prefix[e] = s; cursor[e] = s; s += cnt[e];
      int mts = (cnt[e] + 127) >> 7;
      for (int m = 0; m < mts; ++m) ttab[nt++] = ((u32)e << 16) | (u32)m;
    }
    prefix[16] = s;
    *ntt = nt;
  }
}

__global__ void scatter_k(const int2* __restrict__ topidx, int* __restrict__ cursor,
                          int* __restrict__ slots, int* __restrict__ posof) {
  int t = blockIdx.x * 256 + threadIdx.x;
  int2 e = topidx[t];
  int p0 = atomicAdd(&cursor[e.x], 1); slots[p0] = t * 2 + 0; posof[t * 2 + 0] = p0;
  int p1 = atomicAdd(&cursor[e.y], 1); slots[p1] = t * 2 + 1; posof[t * 2 + 1] = p1;
}

// swizzle constant per row: spreads frag-read chunks to 2-way (free) bank aliasing
__device__ __forceinline__ int rswz(int r) { return (r & 3) ^ ((r >> 2) & 1); }

// ---------------- grouped GEMM 1: H = relu(gather(xb) @ W1 + b1) ----------------
// grid (DHID/128, MAXTILES), block 256. 2-phase double-buffered, BK=32.
__global__ __launch_bounds__(256) void mlp1_k(
    const u16* __restrict__ xb, const u16* __restrict__ W1T,
    const float* __restrict__ b1, const int* __restrict__ slots,
    const int* __restrict__ prefix, const int* __restrict__ cnt,
    const u32* __restrict__ ttab, const int* __restrict__ ntt,
    u16* __restrict__ H) {
  const int ti = blockIdx.y;
  if (ti >= *ntt) return;
  const u32 ent = ttab[ti];
  const int e = (int)(ent >> 16), mt = (int)(ent & 0xffffu);
  const int cn = cnt[e], base = prefix[e];
  const int n0 = blockIdx.x * 128;
  __shared__ __align__(16) u16 As[2][128 * BK], Bs[2][128 * BK];
  const int tid = threadIdx.x, lane = tid & 63, wid = tid >> 6;
  const int wm = (wid >> 1) * 64, wn = (wid & 1) * 64;
  const int lr4 = lane >> 2, lc = lane & 3;
  // staging source addresses (bytes): 2 A + 2 B gl16 per wave, 16 rows each
  size_t asrc[2], bsrc[2];
#pragma unroll
  for (int i = 0; i < 2; ++i) {
    int row = wid * 32 + i * 16 + lr4;               // tile-local row 0..127
    int gch = lc ^ rswz(row);                        // pre-swizzled global chunk
    int sidx = imin(base + mt * 128 + row, NSLOT - 1);
    int tok = slots[sidx] >> 1;
    asrc[i] = (size_t)tok * (DIN * 2) + (size_t)gch * 16;
    bsrc[i] = ((size_t)e * DHID + n0 + row) * (DIN * 2) + (size_t)gch * 16;
  }
  // fragment LDS offsets (u16 units), swizzled read side
  int aoff[4], boff[4];
#pragma unroll
  for (int m = 0; m < 4; ++m) {
    int r = wm + m * 16 + (lane & 15);
    aoff[m] = r * BK + (((lane >> 4) ^ rswz(r)) * 8);
  }
#pragma unroll
  for (int n = 0; n < 4; ++n) {
    int r = wn + n * 16 + (lane & 15);
    boff[n] = r * BK + (((lane >> 4) ^ rswz(r)) * 8);
  }
  f32x4 acc[4][4];
#pragma unroll
  for (int m = 0; m < 4; ++m)
#pragma unroll
    for (int n = 0; n < 4; ++n) acc[m][n] = (f32x4){0.f, 0.f, 0.f, 0.f};

#define STAGE1(buf, kt)                                                          \
  {                                                                              \
    _Pragma("unroll")                                                            \
    for (int i = 0; i < 2; ++i)                                                  \
      gl16((const char*)xb + asrc[i] + (size_t)(kt) * 64,                        \
           &As[buf][(wid * 32 + i * 16) * BK]);                                  \
    _Pragma("unroll")                                                            \
    for (int i = 0; i < 2; ++i)                                                  \
      gl16((const char*)W1T + bsrc[i] + (size_t)(kt) * 64,                       \
           &Bs[buf][(wid * 32 + i * 16) * BK]);                                  \
  }

  STAGE1(0, 0);
  const int NKT = DIN / BK;
  for (int kt = 0; kt < NKT; ++kt) {
    __syncthreads();                       // stage(kt) landed; reads(kt-1) done
    if (kt + 1 < NKT) STAGE1((kt + 1) & 1, kt + 1);
    __builtin_amdgcn_sched_barrier(0);     // keep prefetch issue ahead of compute
    const u16* ab = As[kt & 1];
    const u16* bb = Bs[kt & 1];
    short8v av[4], bv[4];
#pragma unroll
    for (int m = 0; m < 4; ++m) av[m] = *(const short8v*)&ab[aoff[m]];
#pragma unroll
    for (int n = 0; n < 4; ++n) bv[n] = *(const short8v*)&bb[boff[n]];
#pragma unroll
    for (int m = 0; m < 4; ++m)
#pragma unroll
      for (int n = 0; n < 4; ++n)
        acc[m][n] = __builtin_amdgcn_mfma_f32_16x16x32_bf16(av[m], bv[n], acc[m][n], 0, 0, 0);
  }
  const float* b1e = b1 + e * DHID;
  const int rbase = mt * 128;
#pragma unroll
  for (int m = 0; m < 4; ++m)
#pragma unroll
    for (int j = 0; j < 4; ++j) {
      int row = wm + m * 16 + (lane >> 4) * 4 + j;
      if (rbase + row < cn) {
        size_t orow = (size_t)(base + rbase + row) * DHID;
#pragma unroll
        for (int n = 0; n < 4; ++n) {
          int col = n0 + wn + n * 16 + (lane & 15);
          float v = acc[m][n][j] + b1e[col];
          H[orow + col] = f2b(fmaxf(v, 0.f));
        }
      }
    }
}

// ---------------- grouped GEMM 2: pout = w * (H @ W2 + b2) ----------------
// grid (DOUT/128, MAXTILES), block 256. 2-phase double-buffered, BK=32.
__global__ __launch_bounds__(256) void mlp2_k(
    const u16* __restrict__ H, const u16* __restrict__ W2T,
    const float* __restrict__ b2, const int* __restrict__ slots,
    const int* __restrict__ prefix, const int* __restrict__ cnt,
    const u32* __restrict__ ttab, const int* __restrict__ ntt,
    const float* __restrict__ topw, float* __restrict__ pout) {
  const int ti = blockIdx.y;
  if (ti >= *ntt) return;
  const u32 ent = ttab[ti];
  const int e = (int)(ent >> 16), mt = (int)(ent & 0xffffu);
  const int cn = cnt[e], base = prefix[e];
  const int n0 = blockIdx.x * 128;
  __shared__ __align__(16) u16 As[2][128 * BK], Bs[2][128 * BK];
  const int tid = threadIdx.x, lane = tid & 63, wid = tid >> 6;
  const int wm = (wid >> 1) * 64, wn = (wid & 1) * 64;
  const int lr4 = lane >> 2, lc = lane & 3;
  size_t asrc[2], bsrc[2];
#pragma unroll
  for (int i = 0; i < 2; ++i) {
    int row = wid * 32 + i * 16 + lr4;
    int gch = lc ^ rswz(row);
    int sidx = imin(base + mt * 128 + row, NSLOT - 1);
    asrc[i] = (size_t)sidx * (DHID * 2) + (size_t)gch * 16;
    bsrc[i] = ((size_t)e * DOUT + n0 + row) * (DHID * 2) + (size_t)gch * 16;
  }
  int aoff[4], boff[4];
#pragma unroll
  for (int m = 0; m < 4; ++m) {
    int r = wm + m * 16 + (lane & 15);
    aoff[m] = r * BK + (((lane >> 4) ^ rswz(r)) * 8);
  }
#pragma unroll
  for (int n = 0; n < 4; ++n) {
    int r = wn + n * 16 + (lane & 15);
    boff[n] = r * BK + (((lane >> 4) ^ rswz(r)) * 8);
  }
  f32x4 acc[4][4];
#pragma unroll
  for (int m = 0; m < 4; ++m)
#pragma unroll
    for (int n = 0; n < 4; ++n) acc[m][n] = (f32x4){0.f, 0.f, 0.f, 0.f};

#define STAGE2(buf, kt)                                                          \
  {                                                                              \
    _Pragma("unroll")                                                            \
    for (int i = 0; i < 2; ++i)                                                  \
      gl16((const char*)H + asrc[i] + (size_t)(kt) * 64,                         \
           &As[buf][(wid * 32 + i * 16) * BK]);                                  \
    _Pragma("unroll")                                                            \
    for (int i = 0; i < 2; ++i)                                                  \
      gl16((const char*)W2T + bsrc[i] + (size_t)(kt) * 64,                       \
           &Bs[buf][(wid * 32 + i * 16) * BK]);                                  \
  }

  STAGE2(0, 0);
  const int NKT = DHID / BK;
  for (int kt = 0; kt < NKT; ++kt) {
    __syncthreads();
    if (kt + 1 < NKT) STAGE2((kt + 1) & 1, kt + 1);
    __builtin_amdgcn_sched_barrier(0);
    const u16* ab = As[kt & 1];
    const u16* bb = Bs[kt & 1];
    short8v av[4], bv[4];
#pragma unroll
    for (int m = 0; m < 4; ++m) av[m] = *(const short8v*)&ab[aoff[m]];
#pragma unroll
    for (int n = 0; n < 4; ++n) bv[n] = *(const short8v*)&bb[boff[n]];
#pragma unroll
    for (int m = 0; m < 4; ++m)
#pragma unroll
      for (int n = 0; n < 4; ++n)
        acc[m][n] = __builtin_amdgcn_mfma_f32_16x16x32_bf16(av[m], bv[n], acc[m][n], 0, 0, 0);
  }
  const float* b2e = b2 + e * DOUT;
  const int rbase = mt * 128;
#pragma unroll
  for (int m = 0; m < 4; ++m)
#pragma unroll
    for (int j = 0; j < 4; ++j) {
      int row = wm + m * 16 + (lane >> 4) * 4 + j;
      if (rbase + row < cn) {
        int spos = base + rbase + row;
        int sc = slots[spos];
        float w = topw[sc];
        size_t orow = (size_t)spos * DOUT;
#pragma unroll
        for (int n = 0; n < 4; ++n) {
          int col = n0 + wn + n * 16 + (lane & 15);
          pout[orow + col] = w * (acc[m][n][j] + b2e[col]);
        }
      }
    }
}

// ---------------- combine: out[t] = pout[pos(t,0)] + pout[pos(t,1)] ----------------
__global__ void combine_k(const float* __restrict__ pout, const int* __restrict__ posof,
                          float* __restrict__ out) {
  int t = blockIdx.x;
  int p0 = posof[t * 2], p1 = posof[t * 2 + 1];
  const float4* r0 = (const float4*)(pout + (size_t)p0 * DOUT);
  const float4* r1 = (const float4*)(pout + (size_t)p1 * DOUT);
  float4 a = r0[threadIdx.x], b = r1[threadIdx.x];
  float4 o; o.x = a.x + b.x; o.y = a.y + b.y; o.z = a.z + b.z; o.w = a.w + b.w;
  ((float4*)(out + (size_t)t * DOUT))[threadIdx.x] = o;
}

extern "C" void kernel_launch(void* const* d_in, const int* in_sizes, int n_in,
                              void* d_out, int out_size, void* d_ws, size_t ws_size,
                              hipStream_t stream) {
  const float* x  = (const float*)d_in[0];
  const float* Wg = (const float*)d_in[1];
  const float* W1 = (const float*)d_in[2];
  const float* b1 = (const float*)d_in[3];
  const float* W2 = (const float*)d_in[4];
  const float* b2 = (const float*)d_in[5];
  float* out = (float*)d_out;
  char* ws = (char*)d_ws;

  int*    cnt    = (int*)(ws + OFF_CNT);
  int*    cursor = (int*)(ws + OFF_CURSOR);
  int*    prefix = (int*)(ws + OFF_PREFIX);
  u32*    ttab   = (u32*)(ws + OFF_TTAB);
  int*    ntt    = (int*)(ws + OFF_NTT);
  int2*   topidx = (int2*)(ws + OFF_TOPIDX);
  float2* topw2  = (float2*)(ws + OFF_TOPW);
  float*  topw   = (float*)(ws + OFF_TOPW);
  int*    slots  = (int*)(ws + OFF_SLOTS);
  int*    posof  = (int*)(ws + OFF_POSOF);
  u16*    xb     = (u16*)(ws + OFF_XB);
  u16*    W1T    = (u16*)(ws + OFF_W1T);
  u16*    W2T    = (u16*)(ws + OFF_W2T);
  u16*    H      = (u16*)(ws + OFF_H);
  float*  pout   = (float*)(ws + OFF_POUT);

  (void)hipMemsetAsync(ws, 0, 256, stream);  // zero cnt/cursor/prefix region

  convx_k<<<4096, 256, 0, stream>>>(x, xb);
  transpose_conv_k<<<dim3(DHID / 64, DIN / 64, NE), 256, 0, stream>>>(W1, W1T, DIN, DHID);
  transpose_conv_k<<<dim3(DHID / 64 / 2, DIN / 64 * 2, NE), 256, 0, stream>>>(W2, W2T, DHID, DOUT);
  gating2_k<<<256, 256, 0, stream>>>(x, Wg, topidx, topw2, cnt);
  prefix_k<<<1, 64, 0, stream>>>(cnt, prefix, cursor, ttab, ntt);
  scatter_k<<<BQ / 256, 256, 0, stream>>>(topidx, cursor, slots, posof);
  mlp1_k<<<dim3(DHID / 128, MAXTILES), 256, 0, stream>>>(xb, W1T, b1, slots, prefix, cnt, ttab, ntt, H);
  mlp2_k<<<dim3(DOUT / 128, MAXTILES), 256, 0, stream>>>(H, W2T, b2, slots, prefix, cnt, ttab, ntt, topw, pout);
  combine_k<<<BQ, 256, 0, stream>>>(pout, posof, out);
}

// Round 5
// 427.097 us; speedup vs baseline: 1.5781x; 1.0777x over previous
//
#include <hip/hip_runtime.h>

typedef unsigned short u16;
typedef unsigned int   u32;

typedef __attribute__((ext_vector_type(8))) short short8v;
typedef __attribute__((ext_vector_type(4))) float f32x4;

// ---------------- problem constants ----------------
#define BQ   8192
#define DIN  1024
#define DHID 2048
#define DOUT 1024
#define NE   16
#define NSLOT (BQ*2)
#define MAXT 144

// ---------------- ws layout (bytes) ----------------
#define OFF_CNT    ((size_t)0)
#define OFF_CURSOR ((size_t)64)
#define OFF_PREFIX ((size_t)128)
#define OFF_TTAB   ((size_t)512)                     // u32[144]
#define OFF_NTT    ((size_t)1280)                    // int
#define OFF_TOPIDX ((size_t)4096)
#define OFF_TOPW   (OFF_TOPIDX + (size_t)65536)
#define OFF_SLOTS  (OFF_TOPW   + (size_t)65536)
#define OFF_POSOF  (OFF_SLOTS  + (size_t)65536)
#define MB (size_t)(1u<<20)
#define OFF_XB     (1*MB)
#define OFF_W1T    (OFF_XB  + 16*MB)
#define OFF_W2T    (OFF_W1T + 64*MB)
#define OFF_H      (OFF_W2T + 64*MB)
#define OFF_POUT   (OFF_H   + 64*MB)

__device__ __forceinline__ u16 f2b(float f) {        // f32 -> bf16 RNE
  u32 u = __float_as_uint(f);
  u += 0x7fffu + ((u >> 16) & 1u);
  return (u16)(u >> 16);
}

__device__ __forceinline__ void gl16(const void* g, void* l) {
  __builtin_amdgcn_global_load_lds(
      (const __attribute__((address_space(1))) u32*)g,
      (__attribute__((address_space(3))) u32*)l, 16, 0, 0);
}

__device__ __forceinline__ int imin(int a, int b) { return a < b ? a : b; }

// per-row 16B-chunk XOR swizzle (4 chunks per 64B row)
__device__ __forceinline__ int rswz(int r) { return (r & 3) ^ ((r >> 2) & 1); }

// bijective XCD-chunked block swizzle (m204); bx-major decode outside
__device__ __forceinline__ int xcd_swz(int L, int total) {
  int q = total >> 3, r = total & 7;
  int c = L & 7, p = L >> 3;
  return (c < r ? c * (q + 1) : r * (q + 1) + (c - r) * q) + p;
}

// ---------------- prepass: x -> bf16 ----------------
__global__ void convx_k(const float* __restrict__ in, u16* __restrict__ out) {
  int i = blockIdx.x * 256 + threadIdx.x;
  const float4* ip = (const float4*)in;
  float4 a = ip[i * 2], b = ip[i * 2 + 1];
  union { u16 u[8]; uint4 v; } r;
  r.u[0]=f2b(a.x); r.u[1]=f2b(a.y); r.u[2]=f2b(a.z); r.u[3]=f2b(a.w);
  r.u[4]=f2b(b.x); r.u[5]=f2b(b.y); r.u[6]=f2b(b.z); r.u[7]=f2b(b.w);
  ((uint4*)out)[i] = r.v;
}

// ------- prepass: per-expert transpose+convert: in[R][C] f32 -> out[C][R] bf16 -------
__global__ void transpose_conv_k(const float* __restrict__ in, u16* __restrict__ out,
                                 int R, int C) {
  __shared__ __align__(16) u16 tile[64][68];
  const int e = blockIdx.z;
  const float* ip = in + (size_t)e * R * C;
  u16* op = out + (size_t)e * R * C;
  const int r0 = blockIdx.y * 64, c0 = blockIdx.x * 64;
  const int tr = threadIdx.x >> 4, tc = threadIdx.x & 15;
#pragma unroll
  for (int i = 0; i < 4; ++i) {
    int r = tr + i * 16;
    float4 v = *(const float4*)(ip + (size_t)(r0 + r) * C + c0 + tc * 4);
    ushort4 b; b.x=f2b(v.x); b.y=f2b(v.y); b.z=f2b(v.z); b.w=f2b(v.w);
    *(ushort4*)&tile[r][tc * 4] = b;
  }
  __syncthreads();
#pragma unroll
  for (int i = 0; i < 4; ++i) {
    int c = i * 16 + (threadIdx.x >> 4);
    int rq = threadIdx.x & 15;
    ushort4 b;
    b.x = tile[rq*4+0][c]; b.y = tile[rq*4+1][c];
    b.z = tile[rq*4+2][c]; b.w = tile[rq*4+3][c];
    *(ushort4*)(op + (size_t)(c0 + c) * R + r0 + rq * 4) = b;
  }
}

// ---------------- gating v2: Wg in LDS, 8 threads/token, fp64 accum ----------------
__global__ __launch_bounds__(256) void gating2_k(
    const float* __restrict__ x, const float* __restrict__ Wg,
    int2* __restrict__ topidx, float2* __restrict__ topw, int* __restrict__ cnt) {
  __shared__ __align__(16) float wg[1024 * 16];
  __shared__ int hist[16];
  const int tid = threadIdx.x;
  const int t0 = blockIdx.x * 32;
  if (tid < 16) hist[tid] = 0;
  for (int idx = tid; idx < 4096; idx += 256) {
    int k = idx >> 2, c = idx & 3;
    float4 v = ((const float4*)Wg)[idx];
    int pc = c ^ ((k >> 7) & 3);
    *(float4*)&wg[k * 16 + pc * 4] = v;
  }
  __syncthreads();
  const int tt = tid >> 3, q = tid & 7;
  const int f = q & 3;
  double p[16];
#pragma unroll
  for (int e = 0; e < 16; ++e) p[e] = 0.0;
  const float4* xr4 = (const float4*)(x + (size_t)(t0 + tt) * DIN + q * 128);
  for (int jj = 0; jj < 32; ++jj) {
    float4 xv = xr4[jj];
#pragma unroll
    for (int u = 0; u < 4; ++u) {
      int row = q * 128 + jj * 4 + u;
      float xs = (u == 0) ? xv.x : (u == 1) ? xv.y : (u == 2) ? xv.z : xv.w;
      double xd = (double)xs;
#pragma unroll
      for (int c = 0; c < 4; ++c) {
        float4 w = *(const float4*)&wg[row * 16 + (c ^ f) * 4];
        p[c * 4 + 0] += xd * (double)w.x;
        p[c * 4 + 1] += xd * (double)w.y;
        p[c * 4 + 2] += xd * (double)w.z;
        p[c * 4 + 3] += xd * (double)w.w;
      }
    }
  }
#pragma unroll
  for (int e = 0; e < 16; ++e) {
    double v = p[e];
    v += __shfl_xor(v, 1);
    v += __shfl_xor(v, 2);
    v += __shfl_xor(v, 4);
    p[e] = v;
  }
  if (q == 0) {
    double m0 = -1e300, m1 = -1e300; int i0 = 0, i1 = 0;
#pragma unroll
    for (int e = 0; e < 16; ++e) {
      double v = p[e];
      if (v > m0) { m1 = m0; i1 = i0; m0 = v; i0 = e; }
      else if (v > m1) { m1 = v; i1 = e; }
    }
    double r = exp(m1 - m0);
    double w0 = 1.0 / (1.0 + r);
    int t = t0 + tt;
    topidx[t] = make_int2(i0, i1);
    topw[t] = make_float2((float)w0, (float)(r / (1.0 + r)));
    atomicAdd(&hist[i0], 1);
    atomicAdd(&hist[i1], 1);
  }
  __syncthreads();
  if (tid < 16 && hist[tid] > 0) atomicAdd(&cnt[tid], hist[tid]);
}

// prefix + compact tile table: entries (e<<16)|mt, mt over ceil(cnt/128)
__global__ void prefix_k(const int* __restrict__ cnt, int* __restrict__ prefix,
                         int* __restrict__ cursor, u32* __restrict__ ttab,
                         int* __restrict__ ntt) {
  if (threadIdx.x == 0) {
    int s = 0, nt = 0;
    for (int e = 0; e < 16; ++e) {
      prefix[e] = s; cursor[e] = s; s += cnt[e];
      int mts = (cnt[e] + 127) >> 7;
      for (int m = 0; m < mts; ++m) ttab[nt++] = ((u32)e << 16) | (u32)m;
    }
    prefix[16] = s;
    *ntt = nt;
  }
}

__global__ void scatter_k(const int2* __restrict__ topidx, int* __restrict__ cursor,
                          int* __restrict__ slots, int* __restrict__ posof) {
  int t = blockIdx.x * 256 + threadIdx.x;
  int2 e = topidx[t];
  int p0 = atomicAdd(&cursor[e.x], 1); slots[p0] = t * 2 + 0; posof[t * 2 + 0] = p0;
  int p1 = atomicAdd(&cursor[e.y], 1); slots[p1] = t * 2 + 1; posof[t * 2 + 1] = p1;
}

// =====================================================================
// grouped GEMMs: BM=128, BN=256, BK=32, 256 threads (4 waves, wave=128x64)
// 3 LDS buffers, 2-deep prefetch, counted vmcnt(6), 1 barrier / K-tile.
// =====================================================================

// ---------------- GEMM 1: H = relu(gather(xb) @ W1 + b1) ----------------
__global__ __launch_bounds__(256, 2) void mlp1_k(
    const u16* __restrict__ xb, const u16* __restrict__ W1T,
    const float* __restrict__ b1, const int* __restrict__ slots,
    const int* __restrict__ prefix, const int* __restrict__ cnt,
    const u32* __restrict__ ttab, const int* __restrict__ ntt,
    u16* __restrict__ H) {
  const int ntt_ = *ntt;
  const int total = 16 * ntt_;                 // nbx = DHID/BN = 8 -> 8*ntt... (see decode)
  // NOTE: nbx = 8 for mlp1
  const int tot1 = 8 * ntt_;
  int L = blockIdx.x;
  if (L >= tot1) return;
  int w = xcd_swz(L, tot1);
  const int bx = w / ntt_, ti = w - bx * ntt_; // bx-major: consecutive w share bx
  (void)total;
  const u32 ent = ttab[ti];
  const int e = (int)(ent >> 16), mt = (int)(ent & 0xffffu);
  const int cn = cnt[e], base = prefix[e];
  const int n0 = bx * 256;
  __shared__ __align__(16) u16 lds[3][12288];  // per buf: A[128*32] | B[256*32]
  const int tid = threadIdx.x, lane = tid & 63, wid = tid >> 6;
  const int l15 = lane & 15, lq = lane >> 4;

  // staging sources (pre-swizzled 16B chunks; dest is linear per gl16 rule)
  const char* aS[2];
  const char* bS[4];
#pragma unroll
  for (int i = 0; i < 2; ++i) {
    int ca = i * 256 + tid, row = ca >> 2, ch = ca & 3;
    int sidx = imin(base + mt * 128 + row, NSLOT - 1);
    int tok = slots[sidx] >> 1;
    aS[i] = (const char*)xb + (size_t)tok * 2048 + (size_t)((ch ^ rswz(row)) * 16);
  }
#pragma unroll
  for (int i = 0; i < 4; ++i) {
    int cb = i * 256 + tid, row = cb >> 2, ch = cb & 3;
    bS[i] = (const char*)W1T + (size_t)(e * 2048 + n0 + row) * 2048 +
            (size_t)((ch ^ rswz(row)) * 16);
  }
  // fragment LDS offsets (u16 units)
  int aoff[8], boff[4];
#pragma unroll
  for (int m = 0; m < 8; ++m) {
    int r = m * 16 + l15;
    aoff[m] = r * 32 + ((lq ^ rswz(r)) * 8);
  }
#pragma unroll
  for (int n = 0; n < 4; ++n) {
    int r = wid * 64 + n * 16 + l15;
    boff[n] = 4096 + r * 32 + ((lq ^ rswz(r)) * 8);
  }
  f32x4 acc[8][4];
#pragma unroll
  for (int m = 0; m < 8; ++m)
#pragma unroll
    for (int n = 0; n < 4; ++n) acc[m][n] = (f32x4){0.f, 0.f, 0.f, 0.f};

#define STAGE_1(t)                                                         \
  {                                                                        \
    u16* Ab = &lds[(t) % 3][0];                                            \
    _Pragma("unroll")                                                      \
    for (int i = 0; i < 2; ++i)                                            \
      gl16(aS[i] + (size_t)(t) * 64, &Ab[(i * 256 + wid * 64) * 8]);       \
    _Pragma("unroll")                                                      \
    for (int i = 0; i < 4; ++i)                                            \
      gl16(bS[i] + (size_t)(t) * 64, &Ab[4096 * 2 + ((i * 256 + wid * 64) * 8) - 4096]); \
  }
  // (B dest = &lds[t%3][4096 + chunk*8]; expression above keeps one base)

  STAGE_1(0); STAGE_1(1);
  const int NKT = DIN / 32;                    // 32
  for (int kt = 0; kt < NKT; ++kt) {
    if (kt < NKT - 1) asm volatile("s_waitcnt vmcnt(6)" ::: "memory");
    else              asm volatile("s_waitcnt vmcnt(0)" ::: "memory");
    __builtin_amdgcn_s_barrier();
    asm volatile("" ::: "memory");
    if (kt + 2 < NKT) STAGE_1(kt + 2);
    const u16* buf = &lds[kt % 3][0];
    short8v av[8], bv[4];
#pragma unroll
    for (int m = 0; m < 8; ++m) av[m] = *(const short8v*)&buf[aoff[m]];
#pragma unroll
    for (int n = 0; n < 4; ++n) bv[n] = *(const short8v*)&buf[boff[n]];
    __builtin_amdgcn_s_setprio(1);
#pragma unroll
    for (int m = 0; m < 8; ++m)
#pragma unroll
      for (int n = 0; n < 4; ++n)
        acc[m][n] = __builtin_amdgcn_mfma_f32_16x16x32_bf16(av[m], bv[n], acc[m][n], 0, 0, 0);
    __builtin_amdgcn_s_setprio(0);
  }
  const float* b1e = b1 + e * DHID;
  const int rb = mt * 128;
#pragma unroll
  for (int m = 0; m < 8; ++m)
#pragma unroll
    for (int j = 0; j < 4; ++j) {
      int row = m * 16 + lq * 4 + j;
      if (rb + row < cn) {
        size_t orow = (size_t)(base + rb + row) * DHID;
#pragma unroll
        for (int n = 0; n < 4; ++n) {
          int col = n0 + wid * 64 + n * 16 + l15;
          float v = acc[m][n][j] + b1e[col];
          H[orow + col] = f2b(fmaxf(v, 0.f));
        }
      }
    }
}

// ---------------- GEMM 2: pout = w * (H @ W2 + b2) ----------------
__global__ __launch_bounds__(256, 2) void mlp2_k(
    const u16* __restrict__ H, const u16* __restrict__ W2T,
    const float* __restrict__ b2, const int* __restrict__ slots,
    const int* __restrict__ prefix, const int* __restrict__ cnt,
    const u32* __restrict__ ttab, const int* __restrict__ ntt,
    const float* __restrict__ topw, float* __restrict__ pout) {
  const int ntt_ = *ntt;
  const int tot2 = 4 * ntt_;                   // nbx = DOUT/BN = 4
  int L = blockIdx.x;
  if (L >= tot2) return;
  int w = xcd_swz(L, tot2);
  const int bx = w / ntt_, ti = w - bx * ntt_;
  const u32 ent = ttab[ti];
  const int e = (int)(ent >> 16), mt = (int)(ent & 0xffffu);
  const int cn = cnt[e], base = prefix[e];
  const int n0 = bx * 256;
  __shared__ __align__(16) u16 lds[3][12288];
  const int tid = threadIdx.x, lane = tid & 63, wid = tid >> 6;
  const int l15 = lane & 15, lq = lane >> 4;

  const char* aS[2];
  const char* bS[4];
#pragma unroll
  for (int i = 0; i < 2; ++i) {
    int ca = i * 256 + tid, row = ca >> 2, ch = ca & 3;
    int spos = imin(base + mt * 128 + row, NSLOT - 1);
    aS[i] = (const char*)H + (size_t)spos * 4096 + (size_t)((ch ^ rswz(row)) * 16);
  }
#pragma unroll
  for (int i = 0; i < 4; ++i) {
    int cb = i * 256 + tid, row = cb >> 2, ch = cb & 3;
    bS[i] = (const char*)W2T + (size_t)(e * 1024 + n0 + row) * 4096 +
            (size_t)((ch ^ rswz(row)) * 16);
  }
  int aoff[8], boff[4];
#pragma unroll
  for (int m = 0; m < 8; ++m) {
    int r = m * 16 + l15;
    aoff[m] = r * 32 + ((lq ^ rswz(r)) * 8);
  }
#pragma unroll
  for (int n = 0; n < 4; ++n) {
    int r = wid * 64 + n * 16 + l15;
    boff[n] = 4096 + r * 32 + ((lq ^ rswz(r)) * 8);
  }
  f32x4 acc[8][4];
#pragma unroll
  for (int m = 0; m < 8; ++m)
#pragma unroll
    for (int n = 0; n < 4; ++n) acc[m][n] = (f32x4){0.f, 0.f, 0.f, 0.f};

#define STAGE_2(t)                                                         \
  {                                                                        \
    u16* Ab = &lds[(t) % 3][0];                                            \
    _Pragma("unroll")                                                      \
    for (int i = 0; i < 2; ++i)                                            \
      gl16(aS[i] + (size_t)(t) * 64, &Ab[(i * 256 + wid * 64) * 8]);       \
    _Pragma("unroll")                                                      \
    for (int i = 0; i < 4; ++i)                                            \
      gl16(bS[i] + (size_t)(t) * 64, &Ab[4096 + (i * 256 + wid * 64) * 8]); \
  }

  STAGE_2(0); STAGE_2(1);
  const int NKT = DHID / 32;                   // 64
  for (int kt = 0; kt < NKT; ++kt) {
    if (kt < NKT - 1) asm volatile("s_waitcnt vmcnt(6)" ::: "memory");
    else              asm volatile("s_waitcnt vmcnt(0)" ::: "memory");
    __builtin_amdgcn_s_barrier();
    asm volatile("" ::: "memory");
    if (kt + 2 < NKT) STAGE_2(kt + 2);
    const u16* buf = &lds[kt % 3][0];
    short8v av[8], bv[4];
#pragma unroll
    for (int m = 0; m < 8; ++m) av[m] = *(const short8v*)&buf[aoff[m]];
#pragma unroll
    for (int n = 0; n < 4; ++n) bv[n] = *(const short8v*)&buf[boff[n]];
    __builtin_amdgcn_s_setprio(1);
#pragma unroll
    for (int m = 0; m < 8; ++m)
#pragma unroll
      for (int n = 0; n < 4; ++n)
        acc[m][n] = __builtin_amdgcn_mfma_f32_16x16x32_bf16(av[m], bv[n], acc[m][n], 0, 0, 0);
    __builtin_amdgcn_s_setprio(0);
  }
  const float* b2e = b2 + e * DOUT;
  const int rb = mt * 128;
#pragma unroll
  for (int m = 0; m < 8; ++m)
#pragma unroll
    for (int j = 0; j < 4; ++j) {
      int row = m * 16 + lq * 4 + j;
      if (rb + row < cn) {
        int spos = base + rb + row;
        float wgt = topw[slots[spos]];
        size_t orow = (size_t)spos * DOUT;
#pragma unroll
        for (int n = 0; n < 4; ++n) {
          int col = n0 + wid * 64 + n * 16 + l15;
          pout[orow + col] = wgt * (acc[m][n][j] + b2e[col]);
        }
      }
    }
}

// ---------------- combine: out[t] = pout[pos(t,0)] + pout[pos(t,1)] ----------------
__global__ void combine_k(const float* __restrict__ pout, const int* __restrict__ posof,
                          float* __restrict__ out) {
  int t = blockIdx.x;
  int p0 = posof[t * 2], p1 = posof[t * 2 + 1];
  const float4* r0 = (const float4*)(pout + (size_t)p0 * DOUT);
  const float4* r1 = (const float4*)(pout + (size_t)p1 * DOUT);
  float4 a = r0[threadIdx.x], b = r1[threadIdx.x];
  float4 o; o.x = a.x + b.x; o.y = a.y + b.y; o.z = a.z + b.z; o.w = a.w + b.w;
  ((float4*)(out + (size_t)t * DOUT))[threadIdx.x] = o;
}

extern "C" void kernel_launch(void* const* d_in, const int* in_sizes, int n_in,
                              void* d_out, int out_size, void* d_ws, size_t ws_size,
                              hipStream_t stream) {
  const float* x  = (const float*)d_in[0];
  const float* Wg = (const float*)d_in[1];
  const float* W1 = (const float*)d_in[2];
  const float* b1 = (const float*)d_in[3];
  const float* W2 = (const float*)d_in[4];
  const float* b2 = (const float*)d_in[5];
  float* out = (float*)d_out;
  char* ws = (char*)d_ws;

  int*    cnt    = (int*)(ws + OFF_CNT);
  int*    cursor = (int*)(ws + OFF_CURSOR);
  int*    prefix = (int*)(ws + OFF_PREFIX);
  u32*    ttab   = (u32*)(ws + OFF_TTAB);
  int*    ntt    = (int*)(ws + OFF_NTT);
  int2*   topidx = (int2*)(ws + OFF_TOPIDX);
  float2* topw2  = (float2*)(ws + OFF_TOPW);
  float*  topw   = (float*)(ws + OFF_TOPW);
  int*    slots  = (int*)(ws + OFF_SLOTS);
  int*    posof  = (int*)(ws + OFF_POSOF);
  u16*    xb     = (u16*)(ws + OFF_XB);
  u16*    W1T    = (u16*)(ws + OFF_W1T);
  u16*    W2T    = (u16*)(ws + OFF_W2T);
  u16*    H      = (u16*)(ws + OFF_H);
  float*  pout   = (float*)(ws + OFF_POUT);

  (void)hipMemsetAsync(ws, 0, 256, stream);

  convx_k<<<4096, 256, 0, stream>>>(x, xb);
  transpose_conv_k<<<dim3(DHID / 64, DIN / 64, NE), 256, 0, stream>>>(W1, W1T, DIN, DHID);
  transpose_conv_k<<<dim3(DHID / 64 / 2, DIN / 64 * 2, NE), 256, 0, stream>>>(W2, W2T, DHID, DOUT);
  gating2_k<<<256, 256, 0, stream>>>(x, Wg, topidx, topw2, cnt);
  prefix_k<<<1, 64, 0, stream>>>(cnt, prefix, cursor, ttab, ntt);
  scatter_k<<<BQ / 256, 256, 0, stream>>>(topidx, cursor, slots, posof);
  mlp1_k<<<8 * MAXT, 256, 0, stream>>>(xb, W1T, b1, slots, prefix, cnt, ttab, ntt, H);
  mlp2_k<<<4 * MAXT, 256, 0, stream>>>(H, W2T, b2, slots, prefix, cnt, ttab, ntt, topw, pout);
  combine_k<<<BQ, 256, 0, stream>>>(pout, posof, out);
}

// Round 6
// 417.636 us; speedup vs baseline: 1.6139x; 1.0227x over previous
//
#include <hip/hip_runtime.h>

typedef unsigned short u16;
typedef unsigned int   u32;

typedef __attribute__((ext_vector_type(8))) short short8v;
typedef __attribute__((ext_vector_type(4))) float f32x4;

// ---------------- problem constants ----------------
#define BQ   8192
#define DIN  1024
#define DHID 2048
#define DOUT 1024
#define NE   16
#define NSLOT (BQ*2)
#define MAXT 80          // sum ceil(cnt_e/256) <= 64 + 16

// ---------------- ws layout (bytes) ----------------
#define OFF_CNT    ((size_t)0)
#define OFF_CURSOR ((size_t)64)
#define OFF_PREFIX ((size_t)128)
#define OFF_TTAB   ((size_t)512)
#define OFF_NTT    ((size_t)1280)
#define OFF_TOPIDX ((size_t)4096)
#define OFF_TOPW   (OFF_TOPIDX + (size_t)65536)
#define OFF_SLOTS  (OFF_TOPW   + (size_t)65536)
#define OFF_POSOF  (OFF_SLOTS  + (size_t)65536)
#define MB (size_t)(1u<<20)
#define OFF_XB     (1*MB)
#define OFF_W1T    (OFF_XB  + 16*MB)
#define OFF_W2T    (OFF_W1T + 64*MB)
#define OFF_H      (OFF_W2T + 64*MB)
#define OFF_POUT   (OFF_H   + 64*MB)

__device__ __forceinline__ u16 f2b(float f) {        // f32 -> bf16 RNE
  u32 u = __float_as_uint(f);
  u += 0x7fffu + ((u >> 16) & 1u);
  return (u16)(u >> 16);
}

__device__ __forceinline__ void gl16(const void* g, void* l) {
  __builtin_amdgcn_global_load_lds(
      (const __attribute__((address_space(1))) u32*)g,
      (__attribute__((address_space(3))) u32*)l, 16, 0, 0);
}

__device__ __forceinline__ int imin(int a, int b) { return a < b ? a : b; }

// bijective XCD-chunked block swizzle (m204)
__device__ __forceinline__ int xcd_swz(int L, int total) {
  int q = total >> 3, r = total & 7;
  int c = L & 7, p = L >> 3;
  return (c < r ? c * (q + 1) : r * (q + 1) + (c - r) * q) + p;
}

#define FENCE asm volatile("" ::: "memory")
#define BAR   do { FENCE; __builtin_amdgcn_s_barrier(); FENCE; } while (0)
#define MFMA  __builtin_amdgcn_mfma_f32_16x16x32_bf16

// ---------------- prepass: x -> bf16 ----------------
__global__ void convx_k(const float* __restrict__ in, u16* __restrict__ out) {
  int i = blockIdx.x * 256 + threadIdx.x;
  const float4* ip = (const float4*)in;
  float4 a = ip[i * 2], b = ip[i * 2 + 1];
  union { u16 u[8]; uint4 v; } r;
  r.u[0]=f2b(a.x); r.u[1]=f2b(a.y); r.u[2]=f2b(a.z); r.u[3]=f2b(a.w);
  r.u[4]=f2b(b.x); r.u[5]=f2b(b.y); r.u[6]=f2b(b.z); r.u[7]=f2b(b.w);
  ((uint4*)out)[i] = r.v;
}

// ------- prepass: per-expert transpose+convert: in[R][C] f32 -> out[C][R] bf16 -------
__global__ void transpose_conv_k(const float* __restrict__ in, u16* __restrict__ out,
                                 int R, int C) {
  __shared__ __align__(16) u16 tile[64][68];
  const int e = blockIdx.z;
  const float* ip = in + (size_t)e * R * C;
  u16* op = out + (size_t)e * R * C;
  const int r0 = blockIdx.y * 64, c0 = blockIdx.x * 64;
  const int tr = threadIdx.x >> 4, tc = threadIdx.x & 15;
#pragma unroll
  for (int i = 0; i < 4; ++i) {
    int r = tr + i * 16;
    float4 v = *(const float4*)(ip + (size_t)(r0 + r) * C + c0 + tc * 4);
    ushort4 b; b.x=f2b(v.x); b.y=f2b(v.y); b.z=f2b(v.z); b.w=f2b(v.w);
    *(ushort4*)&tile[r][tc * 4] = b;
  }
  __syncthreads();
#pragma unroll
  for (int i = 0; i < 4; ++i) {
    int c = i * 16 + (threadIdx.x >> 4);
    int rq = threadIdx.x & 15;
    ushort4 b;
    b.x = tile[rq*4+0][c]; b.y = tile[rq*4+1][c];
    b.z = tile[rq*4+2][c]; b.w = tile[rq*4+3][c];
    *(ushort4*)(op + (size_t)(c0 + c) * R + r0 + rq * 4) = b;
  }
}

// ---------------- gating v2: Wg in LDS, 8 threads/token, fp64 accum ----------------
__global__ __launch_bounds__(256) void gating2_k(
    const float* __restrict__ x, const float* __restrict__ Wg,
    int2* __restrict__ topidx, float2* __restrict__ topw, int* __restrict__ cnt) {
  __shared__ __align__(16) float wg[1024 * 16];
  __shared__ int hist[16];
  const int tid = threadIdx.x;
  const int t0 = blockIdx.x * 32;
  if (tid < 16) hist[tid] = 0;
  for (int idx = tid; idx < 4096; idx += 256) {
    int k = idx >> 2, c = idx & 3;
    float4 v = ((const float4*)Wg)[idx];
    int pc = c ^ ((k >> 7) & 3);
    *(float4*)&wg[k * 16 + pc * 4] = v;
  }
  __syncthreads();
  const int tt = tid >> 3, q = tid & 7;
  const int f = q & 3;
  double p[16];
#pragma unroll
  for (int e = 0; e < 16; ++e) p[e] = 0.0;
  const float4* xr4 = (const float4*)(x + (size_t)(t0 + tt) * DIN + q * 128);
  for (int jj = 0; jj < 32; ++jj) {
    float4 xv = xr4[jj];
#pragma unroll
    for (int u = 0; u < 4; ++u) {
      int row = q * 128 + jj * 4 + u;
      float xs = (u == 0) ? xv.x : (u == 1) ? xv.y : (u == 2) ? xv.z : xv.w;
      double xd = (double)xs;
#pragma unroll
      for (int c = 0; c < 4; ++c) {
        float4 w = *(const float4*)&wg[row * 16 + (c ^ f) * 4];
        p[c * 4 + 0] += xd * (double)w.x;
        p[c * 4 + 1] += xd * (double)w.y;
        p[c * 4 + 2] += xd * (double)w.z;
        p[c * 4 + 3] += xd * (double)w.w;
      }
    }
  }
#pragma unroll
  for (int e = 0; e < 16; ++e) {
    double v = p[e];
    v += __shfl_xor(v, 1);
    v += __shfl_xor(v, 2);
    v += __shfl_xor(v, 4);
    p[e] = v;
  }
  if (q == 0) {
    double m0 = -1e300, m1 = -1e300; int i0 = 0, i1 = 0;
#pragma unroll
    for (int e = 0; e < 16; ++e) {
      double v = p[e];
      if (v > m0) { m1 = m0; i1 = i0; m0 = v; i0 = e; }
      else if (v > m1) { m1 = v; i1 = e; }
    }
    double r = exp(m1 - m0);
    double w0 = 1.0 / (1.0 + r);
    int t = t0 + tt;
    topidx[t] = make_int2(i0, i1);
    topw[t] = make_float2((float)w0, (float)(r / (1.0 + r)));
    atomicAdd(&hist[i0], 1);
    atomicAdd(&hist[i1], 1);
  }
  __syncthreads();
  if (tid < 16 && hist[tid] > 0) atomicAdd(&cnt[tid], hist[tid]);
}

// prefix + compact tile table: entries (e<<16)|mt, mt over ceil(cnt/256)
__global__ void prefix_k(const int* __restrict__ cnt, int* __restrict__ prefix,
                         int* __restrict__ cursor, u32* __restrict__ ttab,
                         int* __restrict__ ntt) {
  if (threadIdx.x == 0) {
    int s = 0, nt = 0;
    for (int e = 0; e < 16; ++e) {
      prefix[e] = s; cursor[e] = s; s += cnt[e];
      int mts = (cnt[e] + 255) >> 8;
      for (int m = 0; m < mts; ++m) ttab[nt++] = ((u32)e << 16) | (u32)m;
    }
    prefix[16] = s;
    *ntt = nt;
  }
}

__global__ void scatter_k(const int2* __restrict__ topidx, int* __restrict__ cursor,
                          int* __restrict__ slots, int* __restrict__ posof) {
  int t = blockIdx.x * 256 + threadIdx.x;
  int2 e = topidx[t];
  int p0 = atomicAdd(&cursor[e.x], 1); slots[p0] = t * 2 + 0; posof[t * 2 + 0] = p0;
  int p1 = atomicAdd(&cursor[e.y], 1); slots[p1] = t * 2 + 1; posof[t * 2 + 1] = p1;
}

// =====================================================================
// 8-phase 256x256 grouped GEMM (T2+T3+T4+T5). BK=64, 512 thr, 8 waves.
// LDS: 2 buf x { A-low | B-low | A-high | B-high } x 16KB = 128KB.
// Unit = 128 rows x 64 K; staged 1/phase; vmcnt(6) at tile boundary only.
// Row chunk swizzle: LDS chunk kc' holds global chunk kc'^(r&7).
// =====================================================================

// -------- GEMM 1: H = relu(gather(xb) @ W1 + b1) --------
__global__ __launch_bounds__(512, 1) void mlp1_k(
    const u16* __restrict__ xb, const u16* __restrict__ W1T,
    const float* __restrict__ b1, const int* __restrict__ slots,
    const int* __restrict__ prefix, const int* __restrict__ cnt,
    const u32* __restrict__ ttab, const int* __restrict__ ntt,
    u16* __restrict__ H) {
  const int ntt_ = *ntt;
  const int tot = 8 * ntt_;                    // nbx = DHID/256 = 8
  int L = blockIdx.x;
  if (L >= tot) return;
  int w = xcd_swz(L, tot);
  const int bx = w / ntt_, ti = w - bx * ntt_;
  const u32 ent = ttab[ti];
  const int e = (int)(ent >> 16), mt = (int)(ent & 0xffffu);
  const int cn = cnt[e], base = prefix[e];
  const int n0 = bx * 256;
  __shared__ __align__(16) u16 lds[65536];     // 128KB
  const int tid = threadIdx.x, lane = tid & 63, wid = tid >> 6;
  const int l15 = lane & 15, lq = lane >> 4;
  const int tr = tid >> 3;
  const u32 swzo = (u32)(((tid & 7) ^ (tr & 7)) * 16);
  u32 aofs[2][2], bofs[2][2];
#pragma unroll
  for (int h = 0; h < 2; ++h)
#pragma unroll
    for (int j = 0; j < 2; ++j) {
      int r = h * 128 + j * 64 + tr;
      int sidx = imin(base + mt * 256 + r, NSLOT - 1);
      int tok = slots[sidx] >> 1;
      aofs[h][j] = (u32)tok * 2048u + swzo;
      bofs[h][j] = (u32)(e * 2048 + n0 + r) * 2048u + swzo;
    }
  const char* aptr = (const char*)xb;
  const char* bptr = (const char*)W1T;
  int aoff[8], boff[4];
#pragma unroll
  for (int m = 0; m < 8; ++m) {
    int r = m * 16 + l15;
    aoff[m] = (wid >> 2) * 8192 + r * 64 + ((lq ^ (r & 7)) * 8);
  }
#pragma unroll
  for (int n = 0; n < 4; ++n) {
    int r = (wid & 1) * 64 + n * 16 + l15;
    boff[n] = 16384 + ((wid & 3) >> 1) * 8192 + r * 64 + ((lq ^ (r & 7)) * 8);
  }
  f32x4 acc[8][4];
#pragma unroll
  for (int m = 0; m < 8; ++m)
#pragma unroll
    for (int n = 0; n < 4; ++n) acc[m][n] = (f32x4){0.f, 0.f, 0.f, 0.f};

#define STG1(ab, h, tt, cb)                                                     \
  { _Pragma("unroll") for (int j = 0; j < 2; ++j)                                \
      gl16(((ab) ? bptr : aptr) +                                                \
               (size_t)((ab) ? bofs[h][j] : aofs[h][j]) + (size_t)(tt) * 128,    \
           &lds[(cb) + (ab) * 16384 + (h) * 8192 + (j * 512 + wid * 64) * 8]); }

  const int NT = DIN / 64;                     // 16
  // prologue: tile0 all 4 units, tile1 first 3 units
  STG1(0, 0, 0, 0); STG1(1, 0, 0, 0); STG1(0, 1, 0, 0); STG1(1, 1, 0, 0);
  STG1(0, 0, 1, 32768); STG1(1, 0, 1, 32768); STG1(0, 1, 1, 32768);
  asm volatile("s_waitcnt vmcnt(6)" ::: "memory");
  BAR;

  for (int t = 0; t < NT; ++t) {
    const int cb = (t & 1) * 32768;
    const int ncb = cb ^ 32768;
    const u16* bufc = &lds[cb];
    short8v A0[8], A1[8], B0[2], B1[2], C0[2], C1[2];
    // ---- phase 1: read A k0 + B n01 k0; stage B-high(t+1)
#pragma unroll
    for (int m = 0; m < 8; ++m) A0[m] = *(const short8v*)&bufc[aoff[m]];
    B0[0] = *(const short8v*)&bufc[boff[0]];
    B0[1] = *(const short8v*)&bufc[boff[1]];
    if (t + 1 < NT) STG1(1, 1, t + 1, ncb);
    BAR;
    __builtin_amdgcn_s_setprio(1);
#pragma unroll
    for (int m = 0; m < 8; ++m) {
      acc[m][0] = MFMA(A0[m], B0[0], acc[m][0], 0, 0, 0);
      acc[m][1] = MFMA(A0[m], B0[1], acc[m][1], 0, 0, 0);
    }
    __builtin_amdgcn_s_setprio(0);
    BAR;
    // ---- phase 2: read A k1 + B n23 k0; stage A-low(t+2)
#pragma unroll
    for (int m = 0; m < 8; ++m) A1[m] = *(const short8v*)&bufc[aoff[m] ^ 32];
    B1[0] = *(const short8v*)&bufc[boff[2]];
    B1[1] = *(const short8v*)&bufc[boff[3]];
    if (t + 2 < NT) STG1(0, 0, t + 2, cb);
    BAR;
    __builtin_amdgcn_s_setprio(1);
#pragma unroll
    for (int m = 0; m < 8; ++m) {
      acc[m][2] = MFMA(A0[m], B1[0], acc[m][2], 0, 0, 0);
      acc[m][3] = MFMA(A0[m], B1[1], acc[m][3], 0, 0, 0);
    }
    __builtin_amdgcn_s_setprio(0);
    BAR;
    // ---- phase 3: read B k1 (all 4); stage B-low(t+2)
    C0[0] = *(const short8v*)&bufc[boff[0] ^ 32];
    C0[1] = *(const short8v*)&bufc[boff[1] ^ 32];
    C1[0] = *(const short8v*)&bufc[boff[2] ^ 32];
    C1[1] = *(const short8v*)&bufc[boff[3] ^ 32];
    if (t + 2 < NT) STG1(1, 0, t + 2, cb);
    BAR;
    __builtin_amdgcn_s_setprio(1);
#pragma unroll
    for (int m = 0; m < 8; ++m) {
      acc[m][0] = MFMA(A1[m], C0[0], acc[m][0], 0, 0, 0);
      acc[m][1] = MFMA(A1[m], C0[1], acc[m][1], 0, 0, 0);
    }
    __builtin_amdgcn_s_setprio(0);
    BAR;
    // ---- phase 4: stage A-high(t+2); boundary vmcnt
    if (t + 2 < NT) STG1(0, 1, t + 2, cb);
    BAR;
    __builtin_amdgcn_s_setprio(1);
#pragma unroll
    for (int m = 0; m < 8; ++m) {
      acc[m][2] = MFMA(A1[m], C1[0], acc[m][2], 0, 0, 0);
      acc[m][3] = MFMA(A1[m], C1[1], acc[m][3], 0, 0, 0);
    }
    __builtin_amdgcn_s_setprio(0);
    if (t < NT - 2) asm volatile("s_waitcnt vmcnt(6)" ::: "memory");
    else            asm volatile("s_waitcnt vmcnt(0)" ::: "memory");
    BAR;
  }
  const float* b1e = b1 + e * DHID;
#pragma unroll
  for (int m = 0; m < 8; ++m)
#pragma unroll
    for (int j = 0; j < 4; ++j) {
      int rl = (wid >> 2) * 128 + m * 16 + lq * 4 + j;
      if (mt * 256 + rl < cn) {
        size_t orow = (size_t)(base + mt * 256 + rl) * DHID;
#pragma unroll
        for (int n = 0; n < 4; ++n) {
          int col = n0 + (wid & 3) * 64 + n * 16 + l15;
          float v = acc[m][n][j] + b1e[col];
          H[orow + col] = f2b(fmaxf(v, 0.f));
        }
      }
    }
}

// -------- GEMM 2: pout = w * (H @ W2 + b2) --------
__global__ __launch_bounds__(512, 1) void mlp2_k(
    const u16* __restrict__ H, const u16* __restrict__ W2T,
    const float* __restrict__ b2, const int* __restrict__ slots,
    const int* __restrict__ prefix, const int* __restrict__ cnt,
    const u32* __restrict__ ttab, const int* __restrict__ ntt,
    const float* __restrict__ topw, float* __restrict__ pout) {
  const int ntt_ = *ntt;
  const int tot = 4 * ntt_;                    // nbx = DOUT/256 = 4
  int L = blockIdx.x;
  if (L >= tot) return;
  int w = xcd_swz(L, tot);
  const int bx = w / ntt_, ti = w - bx * ntt_;
  const u32 ent = ttab[ti];
  const int e = (int)(ent >> 16), mt = (int)(ent & 0xffffu);
  const int cn = cnt[e], base = prefix[e];
  const int n0 = bx * 256;
  __shared__ __align__(16) u16 lds[65536];
  const int tid = threadIdx.x, lane = tid & 63, wid = tid >> 6;
  const int l15 = lane & 15, lq = lane >> 4;
  const int tr = tid >> 3;
  const u32 swzo = (u32)(((tid & 7) ^ (tr & 7)) * 16);
  u32 aofs[2][2], bofs[2][2];
#pragma unroll
  for (int h = 0; h < 2; ++h)
#pragma unroll
    for (int j = 0; j < 2; ++j) {
      int r = h * 128 + j * 64 + tr;
      int spos = imin(base + mt * 256 + r, NSLOT - 1);
      aofs[h][j] = (u32)spos * 4096u + swzo;
      bofs[h][j] = (u32)(e * 1024 + n0 + r) * 4096u + swzo;
    }
  const char* aptr = (const char*)H;
  const char* bptr = (const char*)W2T;
  int aoff[8], boff[4];
#pragma unroll
  for (int m = 0; m < 8; ++m) {
    int r = m * 16 + l15;
    aoff[m] = (wid >> 2) * 8192 + r * 64 + ((lq ^ (r & 7)) * 8);
  }
#pragma unroll
  for (int n = 0; n < 4; ++n) {
    int r = (wid & 1) * 64 + n * 16 + l15;
    boff[n] = 16384 + ((wid & 3) >> 1) * 8192 + r * 64 + ((lq ^ (r & 7)) * 8);
  }
  f32x4 acc[8][4];
#pragma unroll
  for (int m = 0; m < 8; ++m)
#pragma unroll
    for (int n = 0; n < 4; ++n) acc[m][n] = (f32x4){0.f, 0.f, 0.f, 0.f};

#define STG2(ab, h, tt, cb)                                                     \
  { _Pragma("unroll") for (int j = 0; j < 2; ++j)                                \
      gl16(((ab) ? bptr : aptr) +                                                \
               (size_t)((ab) ? bofs[h][j] : aofs[h][j]) + (size_t)(tt) * 128,    \
           &lds[(cb) + (ab) * 16384 + (h) * 8192 + (j * 512 + wid * 64) * 8]); }

  const int NT = DHID / 64;                    // 32
  STG2(0, 0, 0, 0); STG2(1, 0, 0, 0); STG2(0, 1, 0, 0); STG2(1, 1, 0, 0);
  STG2(0, 0, 1, 32768); STG2(1, 0, 1, 32768); STG2(0, 1, 1, 32768);
  asm volatile("s_waitcnt vmcnt(6)" ::: "memory");
  BAR;

  for (int t = 0; t < NT; ++t) {
    const int cb = (t & 1) * 32768;
    const int ncb = cb ^ 32768;
    const u16* bufc = &lds[cb];
    short8v A0[8], A1[8], B0[2], B1[2], C0[2], C1[2];
#pragma unroll
    for (int m = 0; m < 8; ++m) A0[m] = *(const short8v*)&bufc[aoff[m]];
    B0[0] = *(const short8v*)&bufc[boff[0]];
    B0[1] = *(const short8v*)&bufc[boff[1]];
    if (t + 1 < NT) STG2(1, 1, t + 1, ncb);
    BAR;
    __builtin_amdgcn_s_setprio(1);
#pragma unroll
    for (int m = 0; m < 8; ++m) {
      acc[m][0] = MFMA(A0[m], B0[0], acc[m][0], 0, 0, 0);
      acc[m][1] = MFMA(A0[m], B0[1], acc[m][1], 0, 0, 0);
    }
    __builtin_amdgcn_s_setprio(0);
    BAR;
#pragma unroll
    for (int m = 0; m < 8; ++m) A1[m] = *(const short8v*)&bufc[aoff[m] ^ 32];
    B1[0] = *(const short8v*)&bufc[boff[2]];
    B1[1] = *(const short8v*)&bufc[boff[3]];
    if (t + 2 < NT) STG2(0, 0, t + 2, cb);
    BAR;
    __builtin_amdgcn_s_setprio(1);
#pragma unroll
    for (int m = 0; m < 8; ++m) {
      acc[m][2] = MFMA(A0[m], B1[0], acc[m][2], 0, 0, 0);
      acc[m][3] = MFMA(A0[m], B1[1], acc[m][3], 0, 0, 0);
    }
    __builtin_amdgcn_s_setprio(0);
    BAR;
    C0[0] = *(const short8v*)&bufc[boff[0] ^ 32];
    C0[1] = *(const short8v*)&bufc[boff[1] ^ 32];
    C1[0] = *(const short8v*)&bufc[boff[2] ^ 32];
    C1[1] = *(const short8v*)&bufc[boff[3] ^ 32];
    if (t + 2 < NT) STG2(1, 0, t + 2, cb);
    BAR;
    __builtin_amdgcn_s_setprio(1);
#pragma unroll
    for (int m = 0; m < 8; ++m) {
      acc[m][0] = MFMA(A1[m], C0[0], acc[m][0], 0, 0, 0);
      acc[m][1] = MFMA(A1[m], C0[1], acc[m][1], 0, 0, 0);
    }
    __builtin_amdgcn_s_setprio(0);
    BAR;
    if (t + 2 < NT) STG2(0, 1, t + 2, cb);
    BAR;
    __builtin_amdgcn_s_setprio(1);
#pragma unroll
    for (int m = 0; m < 8; ++m) {
      acc[m][2] = MFMA(A1[m], C1[0], acc[m][2], 0, 0, 0);
      acc[m][3] = MFMA(A1[m], C1[1], acc[m][3], 0, 0, 0);
    }
    __builtin_amdgcn_s_setprio(0);
    if (t < NT - 2) asm volatile("s_waitcnt vmcnt(6)" ::: "memory");
    else            asm volatile("s_waitcnt vmcnt(0)" ::: "memory");
    BAR;
  }
  const float* b2e = b2 + e * DOUT;
#pragma unroll
  for (int m = 0; m < 8; ++m)
#pragma unroll
    for (int j = 0; j < 4; ++j) {
      int rl = (wid >> 2) * 128 + m * 16 + lq * 4 + j;
      if (mt * 256 + rl < cn) {
        int spos = base + mt * 256 + rl;
        float wgt = topw[slots[spos]];
        size_t orow = (size_t)spos * DOUT;
#pragma unroll
        for (int n = 0; n < 4; ++n) {
          int col = n0 + (wid & 3) * 64 + n * 16 + l15;
          pout[orow + col] = wgt * (acc[m][n][j] + b2e[col]);
        }
      }
    }
}

// ---------------- combine: out[t] = pout[pos(t,0)] + pout[pos(t,1)] ----------------
__global__ void combine_k(const float* __restrict__ pout, const int* __restrict__ posof,
                          float* __restrict__ out) {
  int t = blockIdx.x;
  int p0 = posof[t * 2], p1 = posof[t * 2 + 1];
  const float4* r0 = (const float4*)(pout + (size_t)p0 * DOUT);
  const float4* r1 = (const float4*)(pout + (size_t)p1 * DOUT);
  float4 a = r0[threadIdx.x], b = r1[threadIdx.x];
  float4 o; o.x = a.x + b.x; o.y = a.y + b.y; o.z = a.z + b.z; o.w = a.w + b.w;
  ((float4*)(out + (size_t)t * DOUT))[threadIdx.x] = o;
}

extern "C" void kernel_launch(void* const* d_in, const int* in_sizes, int n_in,
                              void* d_out, int out_size, void* d_ws, size_t ws_size,
                              hipStream_t stream) {
  const float* x  = (const float*)d_in[0];
  const float* Wg = (const float*)d_in[1];
  const float* W1 = (const float*)d_in[2];
  const float* b1 = (const float*)d_in[3];
  const float* W2 = (const float*)d_in[4];
  const float* b2 = (const float*)d_in[5];
  float* out = (float*)d_out;
  char* ws = (char*)d_ws;

  int*    cnt    = (int*)(ws + OFF_CNT);
  int*    cursor = (int*)(ws + OFF_CURSOR);
  int*    prefix = (int*)(ws + OFF_PREFIX);
  u32*    ttab   = (u32*)(ws + OFF_TTAB);
  int*    ntt    = (int*)(ws + OFF_NTT);
  int2*   topidx = (int2*)(ws + OFF_TOPIDX);
  float2* topw2  = (float2*)(ws + OFF_TOPW);
  float*  topw   = (float*)(ws + OFF_TOPW);
  int*    slots  = (int*)(ws + OFF_SLOTS);
  int*    posof  = (int*)(ws + OFF_POSOF);
  u16*    xb     = (u16*)(ws + OFF_XB);
  u16*    W1T    = (u16*)(ws + OFF_W1T);
  u16*    W2T    = (u16*)(ws + OFF_W2T);
  u16*    H      = (u16*)(ws + OFF_H);
  float*  pout   = (float*)(ws + OFF_POUT);

  (void)hipMemsetAsync(ws, 0, 256, stream);

  convx_k<<<4096, 256, 0, stream>>>(x, xb);
  transpose_conv_k<<<dim3(DHID / 64, DIN / 64, NE), 256, 0, stream>>>(W1, W1T, DIN, DHID);
  transpose_conv_k<<<dim3(DHID / 64 / 2, DIN / 64 * 2, NE), 256, 0, stream>>>(W2, W2T, DHID, DOUT);
  gating2_k<<<256, 256, 0, stream>>>(x, Wg, topidx, topw2, cnt);
  prefix_k<<<1, 64, 0, stream>>>(cnt, prefix, cursor, ttab, ntt);
  scatter_k<<<BQ / 256, 256, 0, stream>>>(topidx, cursor, slots, posof);
  mlp1_k<<<8 * MAXT, 512, 0, stream>>>(xb, W1T, b1, slots, prefix, cnt, ttab, ntt, H);
  mlp2_k<<<4 * MAXT, 512, 0, stream>>>(H, W2T, b2, slots, prefix, cnt, ttab, ntt, topw, pout);
  combine_k<<<BQ, 256, 0, stream>>>(pout, posof, out);
}